// Round 1
// baseline (1194.144 us; speedup 1.0000x reference)
//
#include <hip/hip_runtime.h>
#include <hip/hip_bf16.h>

typedef __hip_bfloat16 bf16;
typedef __attribute__((ext_vector_type(8))) short s8v;
typedef __attribute__((ext_vector_type(4))) float f4;

#define DEVI __device__ __forceinline__

DEVI f4 mfma16(s8v a, s8v b, f4 c){
  return __builtin_amdgcn_mfma_f32_16x16x32_bf16(a, b, c, 0, 0, 0);
}

constexpr int NPIX = 65536;   // 256*256
constexpr int NDOWN = 1024;   // 32*32

// ---------------- cast weights to bf16 ----------------
// layout in wbf (elements): [0) w_conv1 73728 | [73728) w_conv4a 36864 |
//                           [110592) w_proj 73728 | [184320) w_qkv 110592
__global__ void k_cast_w(const float* __restrict__ w1, const float* __restrict__ w4a,
                         const float* __restrict__ wp, const float* __restrict__ wq,
                         bf16* __restrict__ out){
  int i = blockIdx.x*256 + threadIdx.x;
  if (i < 73728) out[i] = __float2bfloat16(w1[i]);
  else if (i < 110592) out[i] = __float2bfloat16(w4a[i - 73728]);
  else if (i < 184320) out[i] = __float2bfloat16(wp[i - 110592]);
  else if (i < 294912) out[i] = __float2bfloat16(wq[i - 184320]);
}

// ---------------- pack x: fp32 planar -> bf16 K-packed [b][24][65536][8] ----------------
__global__ void k_pack_x(const float* __restrict__ x, bf16* __restrict__ xp){
  __shared__ float t[8][1032];
  int b = blockIdx.z, cb = blockIdx.y, ns = blockIdx.x, tid = threadIdx.x;
  const float* src = x + ((size_t)(b*192 + cb*8))*NPIX + ns*1024;
  #pragma unroll
  for (int i = 0; i < 8; ++i){
    float4 v = *(const float4*)(src + (size_t)i*NPIX + tid*4);
    *(float4*)&t[i][tid*4] = v;
  }
  __syncthreads();
  bf16* dst = xp + (((size_t)(b*24 + cb))*NPIX + ns*1024)*8;
  #pragma unroll
  for (int j = 0; j < 4; ++j){
    int p = j*256 + tid;
    alignas(16) bf16 c8[8];
    #pragma unroll
    for (int i = 0; i < 8; ++i) c8[i] = __float2bfloat16(t[i][p]);
    *(uint4*)(dst + (size_t)p*8) = *(const uint4*)c8;
  }
}

// ---------------- avg-pool 8x8 -> packed bf16 [b][24][1024][8] ----------------
__global__ void k_pool(const bf16* __restrict__ xp, bf16* __restrict__ xdp){
  __shared__ float red[8][32][8];
  int b = blockIdx.z, cb = blockIdx.y, hd = blockIdx.x, tid = threadIdx.x;
  int r = tid >> 5, wd = tid & 31;
  const bf16* src = xp + (((size_t)(b*24 + cb))*NPIX + (hd*8 + r)*256 + wd*8)*8;
  float acc[8] = {0,0,0,0,0,0,0,0};
  #pragma unroll
  for (int ww = 0; ww < 8; ++ww){
    uint4 raw = *(const uint4*)(src + ww*8);
    const bf16* c8 = (const bf16*)&raw;
    #pragma unroll
    for (int i = 0; i < 8; ++i) acc[i] += __bfloat162float(c8[i]);
  }
  #pragma unroll
  for (int i = 0; i < 8; ++i) red[r][wd][i] = acc[i];
  __syncthreads();
  if (tid < 32){
    alignas(16) bf16 o8[8];
    #pragma unroll
    for (int i = 0; i < 8; ++i){
      float s = 0.f;
      #pragma unroll
      for (int rr = 0; rr < 8; ++rr) s += red[rr][tid][i];
      o8[i] = __float2bfloat16(s * (1.0f/64.0f));
    }
    *(uint4*)(xdp + (((size_t)(b*24 + cb))*NDOWN + hd*32 + tid)*8) = *(const uint4*)o8;
  }
}

// ---------------- MFMA GEMM: out[b][m][n] = sum_k W[m][k] * Bp[b][k][n] ----------------
// Bp is K-packed bf16 [b][K/8][npix][8]. Block tile 96(M) x 128(N), 4 waves of 48x64.
// PLANAR=false: packed bf16 out [b][outkb][npix][8]; PLANAR=true: planar fp32, outkb=#channels.
template<int K, bool PLANAR>
__launch_bounds__(256, 2)
__global__ void k_gemm(const bf16* __restrict__ Bp, const bf16* __restrict__ W,
                       void* __restrict__ outp, int npix, int outkb){
  constexpr int KB8 = K/8;
  constexpr int NIT = K/64;
  __shared__ bf16 As[96*72];
  __shared__ bf16 Bs[128*72];
  int tid = threadIdx.x;
  int b = blockIdx.z;
  int m0 = blockIdx.y*96;
  int n0 = blockIdx.x*128;
  int wave = tid >> 6, lane = tid & 63;
  int wm = wave >> 1, wn = wave & 1;
  int lr = lane & 15, kg = lane >> 4;
  f4 acc[3][4] = {};
  const size_t bK = (size_t)b * KB8;
  for (int kt = 0; kt < NIT; ++kt){
    {
      int idx = tid;
      #pragma unroll
      for (int j = 0; j < 3; ++j, idx += 256){
        int m = idx >> 3, kc = idx & 7;
        *(uint4*)&As[m*72 + kc*8] = *(const uint4*)(W + (size_t)(m0 + m)*K + kt*64 + kc*8);
      }
      idx = tid;
      #pragma unroll
      for (int j = 0; j < 4; ++j, idx += 256){
        int kb = idx >> 7, n = idx & 127;
        *(uint4*)&Bs[n*72 + kb*8] = *(const uint4*)(Bp + ((bK + kt*8 + kb)*npix + n0 + n)*8);
      }
    }
    __syncthreads();
    #pragma unroll
    for (int kk = 0; kk < 2; ++kk){
      s8v af[3]; s8v bfr[4];
      int ko = kk*32 + kg*8;
      #pragma unroll
      for (int mf = 0; mf < 3; ++mf) af[mf] = *(const s8v*)&As[(wm*48 + mf*16 + lr)*72 + ko];
      #pragma unroll
      for (int nf = 0; nf < 4; ++nf) bfr[nf] = *(const s8v*)&Bs[(wn*64 + nf*16 + lr)*72 + ko];
      #pragma unroll
      for (int mf = 0; mf < 3; ++mf)
        #pragma unroll
        for (int nf = 0; nf < 4; ++nf)
          acc[mf][nf] = mfma16(af[mf], bfr[nf], acc[mf][nf]);
    }
    __syncthreads();
  }
  int quad = lane >> 4;
  #pragma unroll
  for (int mf = 0; mf < 3; ++mf){
    int mb = m0 + wm*48 + mf*16 + quad*4;
    #pragma unroll
    for (int nf = 0; nf < 4; ++nf){
      int n = n0 + wn*64 + nf*16 + lr;
      if constexpr (PLANAR){
        float* o = (float*)outp;
        #pragma unroll
        for (int r2 = 0; r2 < 4; ++r2)
          o[((size_t)(b*outkb + mb + r2))*npix + n] = acc[mf][nf][r2];
      } else {
        bf16* o = (bf16*)outp;
        alignas(8) bf16 v4[4];
        #pragma unroll
        for (int r2 = 0; r2 < 4; ++r2) v4[r2] = __float2bfloat16(acc[mf][nf][r2]);
        *(uint2*)(o + ((size_t)(b*outkb + (mb >> 3))*npix + n)*8 + (mb & 7)) = *(const uint2*)v4;
      }
    }
  }
}

// ---------------- high branch: strip dw convs + 3x3 dw, fused ----------------
// xp packed [b][24][65536][8] -> hw3p packed [b][48][65536][8]
// kblk 0..23 = 3x3dw(dww branch), kblk 24..47 = 3x3dw(dwh branch)
// v2: channel-planar LDS + sliding-window register reuse.
//   xs:   bf16 planar [ch][28 rows][32 cols] (plane stride 904 bf16: 4*ch bank spread)
//   strip outs: f32 planar [ch][18 rows][20 cols] (plane stride 372: 20*ch bank spread)
__launch_bounds__(256, 4)
__global__ void k_high_dw(const bf16* __restrict__ xp,
    const float* __restrict__ wdww, const float* __restrict__ bdww,
    const float* __restrict__ wdwh, const float* __restrict__ bdwh,
    const float* __restrict__ w3, const float* __restrict__ b3,
    bf16* __restrict__ hw3p){
  __shared__ unsigned short xs[8*904];
  __shared__ float dww_s[8*372];
  __shared__ float dwh_s[8*372];
  __shared__ float wgt[352];
  int t = blockIdx.x, cb = blockIdx.y, b = blockIdx.z, tid = threadIdx.x;
  int r0 = (t >> 4)*16, c0 = (t & 15)*16;

  // ---- weights preload ----
  if (tid < 88){
    int ch = tid/11, j = tid - ch*11;
    wgt[ch*12 + j]      = wdww[(cb*8 + ch)*11 + j];
    wgt[96 + ch*12 + j] = wdwh[(cb*8 + ch)*11 + j];
  } else if (tid < 96){
    int ch = tid - 88;
    wgt[ch*12 + 11]      = bdww[cb*8 + ch];
    wgt[96 + ch*12 + 11] = bdwh[cb*8 + ch];
  } else if (tid < 168){
    int i2 = tid - 96; int ch = i2/9, j = i2 - ch*9;
    wgt[192 + ch*10 + j] = w3[(cb*8 + ch)*9 + j];
  } else if (tid < 240){
    int i2 = tid - 168; int ch = i2/9, j = i2 - ch*9;
    wgt[272 + ch*10 + j] = w3[(192 + cb*8 + ch)*9 + j];
  } else if (tid < 248){
    int ch = tid - 240;
    wgt[192 + ch*10 + 9] = b3[cb*8 + ch];
  } else {
    int ch = tid - 248;
    wgt[272 + ch*10 + 9] = b3[192 + cb*8 + ch];
  }

  // ---- stage x tile (28x28 halo) packed -> planar bf16 ----
  const bf16* src = xp + ((size_t)(b*24 + cb))*NPIX*8;
  for (int i = tid; i < 784; i += 256){
    int r = i/28, c = i - r*28;
    int gr = r0 + r - 6, gc = c0 + c - 6;
    uint4 v = {0,0,0,0};
    if ((unsigned)gr < 256u && (unsigned)gc < 256u)
      v = *(const uint4*)(src + ((size_t)(gr*256 + gc))*8);
    const unsigned short* u = (const unsigned short*)&v;
    #pragma unroll
    for (int ch = 0; ch < 8; ++ch)
      xs[ch*904 + r*32 + c] = u[ch];
  }
  __syncthreads();

  // ---- phase A: strip convs via register sliding window (branchless H/V) ----
  auto strip_task = [&](int ch, int idx, bool isH){
    int ibase = ch*904 + (isH ? (idx + 5)*32 : (idx + 5));
    int istr  = isH ? 1 : 32;
    float vbuf[28];
    #pragma unroll
    for (int i = 0; i < 28; ++i){
      unsigned u = xs[ibase + i*istr];
      vbuf[i] = __uint_as_float(u << 16);
    }
    const float* wb = &wgt[(isH ? 0 : 96) + ch*12];
    float wv[11];
    #pragma unroll
    for (int j = 0; j < 11; ++j) wv[j] = wb[j];
    float bias = wb[11];
    float* ob = (isH ? dww_s : dwh_s) + ch*372 + (isH ? idx*20 : idx);
    int ostr = isH ? 1 : 20;
    int fixedv = (isH ? r0 + idx : c0 + idx) - 1;
    int varb   = (isH ? c0 : r0) - 1;
    bool fok = (unsigned)fixedv < 256u;
    #pragma unroll
    for (int i = 0; i < 18; ++i){
      float s = bias;
      #pragma unroll
      for (int j = 0; j < 11; ++j) s += wv[j]*vbuf[i + j];
      bool ok = fok && ((unsigned)(varb + i) < 256u);
      ob[i*ostr] = ok ? s : 0.f;
    }
  };
  {
    bool isH = tid < 144;
    int t2 = isH ? tid : tid - 144;
    int ch = t2/18, idx = t2 - ch*18;
    strip_task(ch, idx, isH);
  }
  if (tid < 32){
    int t2 = 112 + tid;
    int ch = t2/18, idx = t2 - ch*18;
    strip_task(ch, idx, false);
  }
  __syncthreads();

  // ---- phase B: 3x3 combine, sliding along 8 output cols per thread ----
  {
    int half = tid & 1, rr = (tid >> 1) & 15, ch = tid >> 5;
    const float* wa = &wgt[192 + ch*10];
    const float* wb2 = &wgt[272 + ch*10];
    float acc1[8], acc2[8];
    float ba = wa[9], bb = wb2[9];
    #pragma unroll
    for (int i = 0; i < 8; ++i){ acc1[i] = ba; acc2[i] = bb; }
    #pragma unroll
    for (int dr = 0; dr < 3; ++dr){
      const float* p1 = &dww_s[ch*372 + (rr + dr)*20 + half*8];
      const float* p2 = &dwh_s[ch*372 + (rr + dr)*20 + half*8];
      float4 a0 = *(const float4*)p1;
      float4 a1 = *(const float4*)(p1 + 4);
      float4 a2 = *(const float4*)(p1 + 8);
      float t1v[12] = {a0.x,a0.y,a0.z,a0.w, a1.x,a1.y,a1.z,a1.w, a2.x,a2.y,a2.z,a2.w};
      #pragma unroll
      for (int dc = 0; dc < 3; ++dc){
        float w = wa[dr*3 + dc];
        #pragma unroll
        for (int i = 0; i < 8; ++i) acc1[i] += w * t1v[i + dc];
      }
      float4 b0 = *(const float4*)p2;
      float4 b1 = *(const float4*)(p2 + 4);
      float4 b2 = *(const float4*)(p2 + 8);
      float t2v[12] = {b0.x,b0.y,b0.z,b0.w, b1.x,b1.y,b1.z,b1.w, b2.x,b2.y,b2.z,b2.w};
      #pragma unroll
      for (int dc = 0; dc < 3; ++dc){
        float w = wb2[dr*3 + dc];
        #pragma unroll
        for (int i = 0; i < 8; ++i) acc2[i] += w * t2v[i + dc];
      }
    }
    int gr = r0 + rr, gc = c0 + half*8;
    bf16* o1 = hw3p + (((size_t)(b*48 + cb))*NPIX + gr*256 + gc)*8 + ch;
    bf16* o2 = hw3p + (((size_t)(b*48 + 24 + cb))*NPIX + gr*256 + gc)*8 + ch;
    #pragma unroll
    for (int i = 0; i < 8; ++i){
      o1[i*8] = __float2bfloat16(acc1[i]);
      o2[i*8] = __float2bfloat16(acc2[i]);
    }
  }
}

// ---------------- qkv depthwise 3x3 (+ v max/avg reduction for cb>=48) ----------------
__global__ void k_qkv_dw(const bf16* __restrict__ qkv0p, const float* __restrict__ wdw,
                         float* __restrict__ qkvd, float* __restrict__ vmax, float* __restrict__ vavg){
  __shared__ bf16 xs[34*34*8];
  __shared__ float red[256*8];
  int cb = blockIdx.x, b = blockIdx.y, tid = threadIdx.x;
  for (int i = tid; i < 1156; i += 256){
    int r = i/34, c = i - r*34;
    int gr = r - 1, gc = c - 1;
    uint4 v = {0,0,0,0};
    if ((unsigned)gr < 32u && (unsigned)gc < 32u)
      v = *(const uint4*)(qkv0p + (((size_t)(b*72 + cb))*NDOWN + gr*32 + gc)*8);
    *(uint4*)&xs[i*8] = v;
  }
  __syncthreads();
  float mxv[8], smv[8];
  #pragma unroll
  for (int ch = 0; ch < 8; ++ch){ mxv[ch] = -3.4e38f; smv[ch] = 0.f; }
  for (int j = 0; j < 4; ++j){
    int p = j*256 + tid;
    int r = p >> 5, c = p & 31;
    #pragma unroll
    for (int ch = 0; ch < 8; ++ch){
      float s = 0.f;
      #pragma unroll
      for (int dr = 0; dr < 3; ++dr)
        #pragma unroll
        for (int dc = 0; dc < 3; ++dc)
          s += wdw[(cb*8 + ch)*9 + dr*3 + dc] *
               __bfloat162float(xs[((r + dr)*34 + c + dc)*8 + ch]);
      qkvd[((size_t)(b*576 + cb*8 + ch))*NDOWN + p] = s;
      mxv[ch] = fmaxf(mxv[ch], s);
      smv[ch] += s;
    }
  }
  if (cb >= 48){
    #pragma unroll
    for (int ch = 0; ch < 8; ++ch) red[tid*8 + ch] = mxv[ch];
    __syncthreads();
    for (int st = 128; st > 0; st >>= 1){
      if (tid < st)
        #pragma unroll
        for (int ch = 0; ch < 8; ++ch)
          red[tid*8 + ch] = fmaxf(red[tid*8 + ch], red[(tid + st)*8 + ch]);
      __syncthreads();
    }
    if (tid < 8) vmax[b*192 + (cb - 48)*8 + tid] = red[tid];
    __syncthreads();
    #pragma unroll
    for (int ch = 0; ch < 8; ++ch) red[tid*8 + ch] = smv[ch];
    __syncthreads();
    for (int st = 128; st > 0; st >>= 1){
      if (tid < st)
        #pragma unroll
        for (int ch = 0; ch < 8; ++ch) red[tid*8 + ch] += red[(tid + st)*8 + ch];
      __syncthreads();
    }
    if (tid < 8) vavg[b*192 + (cb - 48)*8 + tid] = red[tid] * (1.0f/1024.0f);
  }
}

// ---------------- attention matrix: normalize q,k rows; softmax(temp * q_hat k_hat^T) ----------------
__global__ void k_attn(const float* __restrict__ qkvd, const float* __restrict__ temp,
                       float* __restrict__ attn){
  __shared__ float inv[48];
  __shared__ float sm[576];
  int bh = blockIdx.x;
  int b = bh >> 3, h = bh & 7;
  const float* qb = qkvd + ((size_t)(b*576 + h*24))*NDOWN;
  const float* kb = qkvd + ((size_t)(b*576 + 192 + h*24))*NDOWN;
  int tid = threadIdx.x, wave = tid >> 6, lane = tid & 63;
  for (int v = wave; v < 48; v += 4){
    const float* p = (v < 24) ? (qb + v*NDOWN) : (kb + (v - 24)*NDOWN);
    float s = 0.f;
    for (int i = lane; i < NDOWN; i += 64){ float xv = p[i]; s += xv*xv; }
    #pragma unroll
    for (int o = 32; o > 0; o >>= 1) s += __shfl_down(s, o);
    if (lane == 0) inv[v] = 1.0f / fmaxf(sqrtf(s), 1e-12f);
  }
  __syncthreads();
  float tp = temp[h];
  for (int pr = tid; pr < 576; pr += 256){
    int c = pr/24, d = pr - c*24;
    const float4* qp = (const float4*)(qb + c*NDOWN);
    const float4* kp = (const float4*)(kb + d*NDOWN);
    float s = 0.f;
    for (int i = 0; i < 256; ++i){
      float4 a = qp[i], e = kp[i];
      s += a.x*e.x + a.y*e.y + a.z*e.z + a.w*e.w;
    }
    sm[pr] = s * inv[c] * inv[24 + d] * tp;
  }
  __syncthreads();
  if (tid < 24){
    float mx = -3.4e38f;
    for (int d = 0; d < 24; ++d) mx = fmaxf(mx, sm[tid*24 + d]);
    float sum = 0.f;
    for (int d = 0; d < 24; ++d) sum += __expf(sm[tid*24 + d] - mx);
    float isum = 1.0f / sum;
    for (int d = 0; d < 24; ++d)
      attn[((size_t)bh)*576 + tid*24 + d] = __expf(sm[tid*24 + d] - mx) * isum;
  }
}

// ---------------- gate: W2 @ vmax + W3 @ vavg ----------------
__global__ void k_gate(const float* __restrict__ vmax, const float* __restrict__ vavg,
                       const float* __restrict__ w2, const float* __restrict__ w3,
                       float* __restrict__ gate){
  __shared__ float vm[192], va[192];
  int b = blockIdx.x, tid = threadIdx.x;
  if (tid < 192){ vm[tid] = vmax[b*192 + tid]; va[tid] = vavg[b*192 + tid]; }
  __syncthreads();
  if (tid < 192){
    float s = 0.f;
    const float* w2r = w2 + tid*192;
    const float* w3r = w3 + tid*192;
    for (int k = 0; k < 192; ++k) s += w2r[k]*vm[k] + w3r[k]*va[k];
    gate[b*192 + tid] = s;
  }
}

// ---------------- low branch: conv4b dw 3x3 + gate + per-head 24x24 attn apply ----------------
__global__ void k_low(const bf16* __restrict__ x4ap, const float* __restrict__ attn,
                      const float* __restrict__ gate, const float* __restrict__ w4b,
                      bf16* __restrict__ hlp){
  __shared__ bf16 xt[3*18*18*8];
  __shared__ float a2[576];
  __shared__ float wt[216];
  __shared__ float vt[24*256];
  int t = blockIdx.x, h = blockIdx.y, b = blockIdx.z, tid = threadIdx.x;
  int r0 = (t >> 4)*16, c0 = (t & 15)*16;
  int ch0 = h*24;
  for (int i = tid; i < 576; i += 256)
    a2[i] = attn[((size_t)(b*8 + h))*576 + i] * gate[b*192 + ch0 + (i % 24)];
  for (int i = tid; i < 216; i += 256) wt[i] = w4b[ch0*9 + i];
  for (int i = tid; i < 972; i += 256){
    int kb = i/324, p = i - kb*324;
    int r = p/18, c = p - r*18;
    int gr = r0 + r - 1, gc = c0 + c - 1;
    uint4 v = {0,0,0,0};
    if ((unsigned)gr < 256u && (unsigned)gc < 256u)
      v = *(const uint4*)(x4ap + (((size_t)(b*24 + h*3 + kb))*NPIX + gr*256 + gc)*8);
    *(uint4*)&xt[i*8] = v;
  }
  __syncthreads();
  {
    int r = tid >> 4, c = tid & 15;
    #pragma unroll
    for (int ch = 0; ch < 24; ++ch){
      int kb = ch >> 3, ci = ch & 7;
      float s = 0.f;
      #pragma unroll
      for (int dr = 0; dr < 3; ++dr)
        #pragma unroll
        for (int dc = 0; dc < 3; ++dc)
          s += wt[ch*9 + dr*3 + dc] *
               __bfloat162float(xt[((kb*18 + r + dr)*18 + c + dc)*8 + ci]);
      vt[ch*256 + tid] = s;
    }
  }
  __syncthreads();
  {
    float o[24];
    #pragma unroll
    for (int cc = 0; cc < 24; ++cc){
      float s = 0.f;
      #pragma unroll
      for (int d = 0; d < 24; ++d) s += a2[cc*24 + d] * vt[d*256 + tid];
      o[cc] = s;
    }
    int n = (r0 + (tid >> 4))*256 + c0 + (tid & 15);
    #pragma unroll
    for (int kb = 0; kb < 3; ++kb){
      alignas(16) bf16 c8[8];
      #pragma unroll
      for (int i = 0; i < 8; ++i) c8[i] = __float2bfloat16(o[kb*8 + i]);
      *(uint4*)(hlp + (((size_t)(b*48 + 24 + h*3 + kb))*NPIX + n)*8) = *(const uint4*)c8;
    }
  }
}

extern "C" void kernel_launch(void* const* d_in, const int* in_sizes, int n_in,
                              void* d_out, int out_size, void* d_ws, size_t ws_size,
                              hipStream_t stream){
  const float* x        = (const float*)d_in[0];
  const float* w_dww    = (const float*)d_in[1];
  const float* b_dww    = (const float*)d_in[2];
  const float* w_dwh    = (const float*)d_in[3];
  const float* b_dwh    = (const float*)d_in[4];
  const float* w_dwhw   = (const float*)d_in[5];
  const float* b_dwhw   = (const float*)d_in[6];
  const float* w_conv1  = (const float*)d_in[7];
  const float* w_qkv    = (const float*)d_in[8];
  const float* w_qkvdw  = (const float*)d_in[9];
  const float* w_conv2  = (const float*)d_in[10];
  const float* w_conv3  = (const float*)d_in[11];
  const float* w_conv4a = (const float*)d_in[12];
  const float* w_conv4b = (const float*)d_in[13];
  const float* w_proj   = (const float*)d_in[14];
  const float* temp     = (const float*)d_in[15];

  char* ws = (char*)d_ws;
  size_t off = 0;
  auto take = [&](size_t bytes)->char*{
    char* r = ws + off;
    off = (off + bytes + 255) & ~(size_t)255;
    return r;
  };
  bf16*  xp    = (bf16*) take((size_t)4*192*65536*2);  // packed x
  bf16*  hw3p  = (bf16*) take((size_t)4*384*65536*2);  // packed high pre-conv1
  bf16*  hlp   = (bf16*) take((size_t)4*384*65536*2);  // packed [high|low] proj input
  bf16*  x4ap  = (bf16*) take((size_t)4*192*65536*2);  // packed conv4a out
  bf16*  xdp   = (bf16*) take((size_t)4*192*1024*2);   // packed pooled x
  bf16*  qkv0p = (bf16*) take((size_t)4*576*1024*2);   // packed qkv 1x1 out
  float* qkvd  = (float*)take((size_t)4*576*1024*4);   // planar qkv post-dw
  float* attn  = (float*)take((size_t)4*8*576*4);
  float* vmax  = (float*)take((size_t)4*192*4);
  float* vavg  = (float*)take((size_t)4*192*4);
  float* gate  = (float*)take((size_t)4*192*4);
  bf16*  wbf   = (bf16*) take((size_t)294912*2);
  if (off > ws_size) return;  // workspace too small: fail loudly via absmax

  k_cast_w<<<1152, 256, 0, stream>>>(w_conv1, w_conv4a, w_proj, w_qkv, wbf);
  k_pack_x<<<dim3(64,24,4), 256, 0, stream>>>(x, xp);
  k_pool<<<dim3(32,24,4), 256, 0, stream>>>(xp, xdp);
  k_gemm<192,false><<<dim3(8,6,4), 256, 0, stream>>>(xdp, wbf + 184320, qkv0p, 1024, 72);
  k_qkv_dw<<<dim3(72,4), 256, 0, stream>>>(qkv0p, w_qkvdw, qkvd, vmax, vavg);
  k_attn<<<32, 256, 0, stream>>>(qkvd, temp, attn);
  k_gate<<<4, 192, 0, stream>>>(vmax, vavg, w_conv2, w_conv3, gate);
  k_high_dw<<<dim3(256,24,4), 256, 0, stream>>>(xp, w_dww, b_dww, w_dwh, b_dwh, w_dwhw, b_dwhw, hw3p);
  k_gemm<384,false><<<dim3(512,2,4), 256, 0, stream>>>(hw3p, wbf, hlp, 65536, 48);
  k_gemm<192,false><<<dim3(512,2,4), 256, 0, stream>>>(xp, wbf + 73728, x4ap, 65536, 24);
  k_low<<<dim3(256,8,4), 256, 0, stream>>>(x4ap, attn, gate, w_conv4b, hlp);
  k_gemm<384,true><<<dim3(512,2,4), 256, 0, stream>>>(hlp, wbf + 110592, d_out, 65536, 192);
}

// Round 2
// 1026.451 us; speedup vs baseline: 1.1634x; 1.1634x over previous
//
#include <hip/hip_runtime.h>
#include <hip/hip_bf16.h>

typedef __hip_bfloat16 bf16;
typedef __attribute__((ext_vector_type(8))) short s8v;
typedef __attribute__((ext_vector_type(4))) float f4;

#define DEVI __device__ __forceinline__

DEVI f4 mfma16(s8v a, s8v b, f4 c){
  return __builtin_amdgcn_mfma_f32_16x16x32_bf16(a, b, c, 0, 0, 0);
}

constexpr int NPIX = 65536;   // 256*256
constexpr int NDOWN = 1024;   // 32*32

// ---------------- cast weights to bf16 ----------------
// layout in wbf (elements): [0) w_conv1 73728 | [73728) w_conv4a 36864 |
//                           [110592) w_proj 73728 | [184320) w_qkv 110592
__global__ void k_cast_w(const float* __restrict__ w1, const float* __restrict__ w4a,
                         const float* __restrict__ wp, const float* __restrict__ wq,
                         bf16* __restrict__ out){
  int i = blockIdx.x*256 + threadIdx.x;
  if (i < 73728) out[i] = __float2bfloat16(w1[i]);
  else if (i < 110592) out[i] = __float2bfloat16(w4a[i - 73728]);
  else if (i < 184320) out[i] = __float2bfloat16(wp[i - 110592]);
  else if (i < 294912) out[i] = __float2bfloat16(wq[i - 184320]);
}

// ---------------- pack x: fp32 planar -> bf16 K-packed [b][24][65536][8] ----------------
__global__ void k_pack_x(const float* __restrict__ x, bf16* __restrict__ xp){
  __shared__ float t[8][1032];
  int b = blockIdx.z, cb = blockIdx.y, ns = blockIdx.x, tid = threadIdx.x;
  const float* src = x + ((size_t)(b*192 + cb*8))*NPIX + ns*1024;
  #pragma unroll
  for (int i = 0; i < 8; ++i){
    float4 v = *(const float4*)(src + (size_t)i*NPIX + tid*4);
    *(float4*)&t[i][tid*4] = v;
  }
  __syncthreads();
  bf16* dst = xp + (((size_t)(b*24 + cb))*NPIX + ns*1024)*8;
  #pragma unroll
  for (int j = 0; j < 4; ++j){
    int p = j*256 + tid;
    alignas(16) bf16 c8[8];
    #pragma unroll
    for (int i = 0; i < 8; ++i) c8[i] = __float2bfloat16(t[i][p]);
    *(uint4*)(dst + (size_t)p*8) = *(const uint4*)c8;
  }
}

// ---------------- avg-pool 8x8 -> packed bf16 [b][24][1024][8] ----------------
__global__ void k_pool(const bf16* __restrict__ xp, bf16* __restrict__ xdp){
  __shared__ float red[8][32][8];
  int b = blockIdx.z, cb = blockIdx.y, hd = blockIdx.x, tid = threadIdx.x;
  int r = tid >> 5, wd = tid & 31;
  const bf16* src = xp + (((size_t)(b*24 + cb))*NPIX + (hd*8 + r)*256 + wd*8)*8;
  float acc[8] = {0,0,0,0,0,0,0,0};
  #pragma unroll
  for (int ww = 0; ww < 8; ++ww){
    uint4 raw = *(const uint4*)(src + ww*8);
    const bf16* c8 = (const bf16*)&raw;
    #pragma unroll
    for (int i = 0; i < 8; ++i) acc[i] += __bfloat162float(c8[i]);
  }
  #pragma unroll
  for (int i = 0; i < 8; ++i) red[r][wd][i] = acc[i];
  __syncthreads();
  if (tid < 32){
    alignas(16) bf16 o8[8];
    #pragma unroll
    for (int i = 0; i < 8; ++i){
      float s = 0.f;
      #pragma unroll
      for (int rr = 0; rr < 8; ++rr) s += red[rr][tid][i];
      o8[i] = __float2bfloat16(s * (1.0f/64.0f));
    }
    *(uint4*)(xdp + (((size_t)(b*24 + cb))*NDOWN + hd*32 + tid)*8) = *(const uint4*)o8;
  }
}

// ---------------- MFMA GEMM: out[b][m][n] = sum_k W[m][k] * Bp[b][k][n] ----------------
// Bp is K-packed bf16 [b][K/8][npix][8]. Block tile 96(M) x 128(N), 4 waves of 48x64.
// PLANAR=false: packed bf16 out [b][outkb][npix][8]; PLANAR=true: planar fp32, outkb=#channels.
template<int K, bool PLANAR>
__launch_bounds__(256, 2)
__global__ void k_gemm(const bf16* __restrict__ Bp, const bf16* __restrict__ W,
                       void* __restrict__ outp, int npix, int outkb){
  constexpr int KB8 = K/8;
  constexpr int NIT = K/64;
  __shared__ bf16 As[96*72];
  __shared__ bf16 Bs[128*72];
  int tid = threadIdx.x;
  int b = blockIdx.z;
  int m0 = blockIdx.y*96;
  int n0 = blockIdx.x*128;
  int wave = tid >> 6, lane = tid & 63;
  int wm = wave >> 1, wn = wave & 1;
  int lr = lane & 15, kg = lane >> 4;
  f4 acc[3][4] = {};
  const size_t bK = (size_t)b * KB8;
  for (int kt = 0; kt < NIT; ++kt){
    {
      int idx = tid;
      #pragma unroll
      for (int j = 0; j < 3; ++j, idx += 256){
        int m = idx >> 3, kc = idx & 7;
        *(uint4*)&As[m*72 + kc*8] = *(const uint4*)(W + (size_t)(m0 + m)*K + kt*64 + kc*8);
      }
      idx = tid;
      #pragma unroll
      for (int j = 0; j < 4; ++j, idx += 256){
        int kb = idx >> 7, n = idx & 127;
        *(uint4*)&Bs[n*72 + kb*8] = *(const uint4*)(Bp + ((bK + kt*8 + kb)*npix + n0 + n)*8);
      }
    }
    __syncthreads();
    #pragma unroll
    for (int kk = 0; kk < 2; ++kk){
      s8v af[3]; s8v bfr[4];
      int ko = kk*32 + kg*8;
      #pragma unroll
      for (int mf = 0; mf < 3; ++mf) af[mf] = *(const s8v*)&As[(wm*48 + mf*16 + lr)*72 + ko];
      #pragma unroll
      for (int nf = 0; nf < 4; ++nf) bfr[nf] = *(const s8v*)&Bs[(wn*64 + nf*16 + lr)*72 + ko];
      #pragma unroll
      for (int mf = 0; mf < 3; ++mf)
        #pragma unroll
        for (int nf = 0; nf < 4; ++nf)
          acc[mf][nf] = mfma16(af[mf], bfr[nf], acc[mf][nf]);
    }
    __syncthreads();
  }
  int quad = lane >> 4;
  #pragma unroll
  for (int mf = 0; mf < 3; ++mf){
    int mb = m0 + wm*48 + mf*16 + quad*4;
    #pragma unroll
    for (int nf = 0; nf < 4; ++nf){
      int n = n0 + wn*64 + nf*16 + lr;
      if constexpr (PLANAR){
        float* o = (float*)outp;
        #pragma unroll
        for (int r2 = 0; r2 < 4; ++r2)
          o[((size_t)(b*outkb + mb + r2))*npix + n] = acc[mf][nf][r2];
      } else {
        bf16* o = (bf16*)outp;
        alignas(8) bf16 v4[4];
        #pragma unroll
        for (int r2 = 0; r2 < 4; ++r2) v4[r2] = __float2bfloat16(acc[mf][nf][r2]);
        *(uint2*)(o + ((size_t)(b*outkb + (mb >> 3))*npix + n)*8 + (mb & 7)) = *(const uint2*)v4;
      }
    }
  }
}

// ---------------- high branch: strip dw convs + 3x3 dw, fused ----------------
// xp packed [b][24][65536][8] -> hw3p packed [b][48][65536][8]
// kblk 0..23 = 3x3dw(dww branch), kblk 24..47 = 3x3dw(dwh branch)
// v3: original pixel-packed structure + two bank-verified changes:
//   xs row stride padded 28->29 pixels (enables conflict-free sliding-window
//   strip reads in both H and V orientation); dwwt/dwht pixel stride 8->9
//   (breaks phase-3's 8-way conflict, bank = (2r+9c+ch)%32, ~2-way).
__launch_bounds__(256, 4)
__global__ void k_high_dw(const bf16* __restrict__ xp,
    const float* __restrict__ wdww, const float* __restrict__ bdww,
    const float* __restrict__ wdwh, const float* __restrict__ bdwh,
    const float* __restrict__ w3, const float* __restrict__ b3,
    bf16* __restrict__ hw3p){
  __shared__ bf16 xs[28*29*8];      // [row][col pad29][8ch]
  __shared__ float dwwt[324*9];     // [18*18 pix][ch pad9]
  __shared__ float dwht[324*9];
  int t = blockIdx.x, cb = blockIdx.y, b = blockIdx.z, tid = threadIdx.x;
  int r0 = (t >> 4)*16, c0 = (t & 15)*16;

  // ---- stage x tile (28x28 halo) with padded row stride, uint4 per pixel ----
  const bf16* src = xp + ((size_t)(b*24 + cb))*NPIX*8;
  for (int i = tid; i < 784; i += 256){
    int r = i/28, c = i - r*28;
    int gr = r0 + r - 6, gc = c0 + c - 6;
    uint4 v = {0,0,0,0};
    if ((unsigned)gr < 256u && (unsigned)gc < 256u)
      v = *(const uint4*)(src + ((size_t)(gr*256 + gc))*8);
    *(uint4*)&xs[(r*29 + c)*8] = v;
  }
  __syncthreads();

  // ---- phase A: strip convs via register sliding window ----
  // task id: ch = task&7, idx = task>>3 (idx = output row for H, output col for V)
  auto strip_task = [&](int task, bool isH){
    int ch = task & 7, idx = task >> 3;
    int cg = cb*8 + ch;
    const float* wsrc = isH ? (wdww + cg*11) : (wdwh + cg*11);
    float wv[11];
    #pragma unroll
    for (int j = 0; j < 11; ++j) wv[j] = wsrc[j];
    float bias = isH ? bdww[cg] : bdwh[cg];
    int base = isH ? ((idx + 5)*29)*8 + ch : (idx + 5)*8 + ch;
    int istr = isH ? 8 : 29*8;
    float vbuf[28];
    #pragma unroll
    for (int i = 0; i < 28; ++i)
      vbuf[i] = __bfloat162float(xs[base + i*istr]);
    float* ob = isH ? (dwwt + (idx*18)*9 + ch) : (dwht + idx*9 + ch);
    int ostr = isH ? 9 : 18*9;
    int fixedv = (isH ? r0 : c0) + idx - 1;
    int varb   = (isH ? c0 : r0) - 1;
    bool fok = (unsigned)fixedv < 256u;
    #pragma unroll
    for (int i = 0; i < 18; ++i){
      float s = bias;
      #pragma unroll
      for (int j = 0; j < 11; ++j) s += wv[j]*vbuf[i + j];
      bool ok = fok && ((unsigned)(varb + i) < 256u);
      ob[i*ostr] = ok ? s : 0.f;
    }
  };
  {
    bool isH = tid < 144;
    int task = isH ? tid : tid - 144;   // H tasks 0..143, V tasks 0..111
    strip_task(task, isH);
    if (tid >= 224) strip_task(tid - 112, false);  // V tasks 112..143
  }
  __syncthreads();

  // ---- phase B: 3x3 combine per pixel (stride-9 LDS, ~2-way banks) ----
  {
    int r = tid >> 4, c = tid & 15;
    int n = (r0 + r)*256 + c0 + c;
    alignas(16) bf16 o1[8], o2[8];
    #pragma unroll
    for (int ch = 0; ch < 8; ++ch){
      int cg = cb*8 + ch;
      float s1 = b3[cg], s2 = b3[192 + cg];
      #pragma unroll
      for (int dr = 0; dr < 3; ++dr)
        #pragma unroll
        for (int dc = 0; dc < 3; ++dc){
          int pi = ((r + dr)*18 + c + dc)*9 + ch;
          s1 += w3[cg*9 + dr*3 + dc]         * dwwt[pi];
          s2 += w3[(192 + cg)*9 + dr*3 + dc] * dwht[pi];
        }
      o1[ch] = __float2bfloat16(s1);
      o2[ch] = __float2bfloat16(s2);
    }
    *(uint4*)(hw3p + (((size_t)(b*48 + cb))*NPIX + n)*8)      = *(const uint4*)o1;
    *(uint4*)(hw3p + (((size_t)(b*48 + 24 + cb))*NPIX + n)*8) = *(const uint4*)o2;
  }
}

// ---------------- qkv depthwise 3x3 (+ v max/avg reduction for cb>=48) ----------------
__global__ void k_qkv_dw(const bf16* __restrict__ qkv0p, const float* __restrict__ wdw,
                         float* __restrict__ qkvd, float* __restrict__ vmax, float* __restrict__ vavg){
  __shared__ bf16 xs[34*34*8];
  __shared__ float red[256*8];
  int cb = blockIdx.x, b = blockIdx.y, tid = threadIdx.x;
  for (int i = tid; i < 1156; i += 256){
    int r = i/34, c = i - r*34;
    int gr = r - 1, gc = c - 1;
    uint4 v = {0,0,0,0};
    if ((unsigned)gr < 32u && (unsigned)gc < 32u)
      v = *(const uint4*)(qkv0p + (((size_t)(b*72 + cb))*NDOWN + gr*32 + gc)*8);
    *(uint4*)&xs[i*8] = v;
  }
  __syncthreads();
  float mxv[8], smv[8];
  #pragma unroll
  for (int ch = 0; ch < 8; ++ch){ mxv[ch] = -3.4e38f; smv[ch] = 0.f; }
  for (int j = 0; j < 4; ++j){
    int p = j*256 + tid;
    int r = p >> 5, c = p & 31;
    #pragma unroll
    for (int ch = 0; ch < 8; ++ch){
      float s = 0.f;
      #pragma unroll
      for (int dr = 0; dr < 3; ++dr)
        #pragma unroll
        for (int dc = 0; dc < 3; ++dc)
          s += wdw[(cb*8 + ch)*9 + dr*3 + dc] *
               __bfloat162float(xs[((r + dr)*34 + c + dc)*8 + ch]);
      qkvd[((size_t)(b*576 + cb*8 + ch))*NDOWN + p] = s;
      mxv[ch] = fmaxf(mxv[ch], s);
      smv[ch] += s;
    }
  }
  if (cb >= 48){
    #pragma unroll
    for (int ch = 0; ch < 8; ++ch) red[tid*8 + ch] = mxv[ch];
    __syncthreads();
    for (int st = 128; st > 0; st >>= 1){
      if (tid < st)
        #pragma unroll
        for (int ch = 0; ch < 8; ++ch)
          red[tid*8 + ch] = fmaxf(red[tid*8 + ch], red[(tid + st)*8 + ch]);
      __syncthreads();
    }
    if (tid < 8) vmax[b*192 + (cb - 48)*8 + tid] = red[tid];
    __syncthreads();
    #pragma unroll
    for (int ch = 0; ch < 8; ++ch) red[tid*8 + ch] = smv[ch];
    __syncthreads();
    for (int st = 128; st > 0; st >>= 1){
      if (tid < st)
        #pragma unroll
        for (int ch = 0; ch < 8; ++ch) red[tid*8 + ch] += red[(tid + st)*8 + ch];
      __syncthreads();
    }
    if (tid < 8) vavg[b*192 + (cb - 48)*8 + tid] = red[tid] * (1.0f/1024.0f);
  }
}

// ---------------- attention matrix: normalize q,k rows; softmax(temp * q_hat k_hat^T) ----------------
__global__ void k_attn(const float* __restrict__ qkvd, const float* __restrict__ temp,
                       float* __restrict__ attn){
  __shared__ float inv[48];
  __shared__ float sm[576];
  int bh = blockIdx.x;
  int b = bh >> 3, h = bh & 7;
  const float* qb = qkvd + ((size_t)(b*576 + h*24))*NDOWN;
  const float* kb = qkvd + ((size_t)(b*576 + 192 + h*24))*NDOWN;
  int tid = threadIdx.x, wave = tid >> 6, lane = tid & 63;
  for (int v = wave; v < 48; v += 4){
    const float* p = (v < 24) ? (qb + v*NDOWN) : (kb + (v - 24)*NDOWN);
    float s = 0.f;
    for (int i = lane; i < NDOWN; i += 64){ float xv = p[i]; s += xv*xv; }
    #pragma unroll
    for (int o = 32; o > 0; o >>= 1) s += __shfl_down(s, o);
    if (lane == 0) inv[v] = 1.0f / fmaxf(sqrtf(s), 1e-12f);
  }
  __syncthreads();
  float tp = temp[h];
  for (int pr = tid; pr < 576; pr += 256){
    int c = pr/24, d = pr - c*24;
    const float4* qp = (const float4*)(qb + c*NDOWN);
    const float4* kp = (const float4*)(kb + d*NDOWN);
    float s = 0.f;
    for (int i = 0; i < 256; ++i){
      float4 a = qp[i], e = kp[i];
      s += a.x*e.x + a.y*e.y + a.z*e.z + a.w*e.w;
    }
    sm[pr] = s * inv[c] * inv[24 + d] * tp;
  }
  __syncthreads();
  if (tid < 24){
    float mx = -3.4e38f;
    for (int d = 0; d < 24; ++d) mx = fmaxf(mx, sm[tid*24 + d]);
    float sum = 0.f;
    for (int d = 0; d < 24; ++d) sum += __expf(sm[tid*24 + d] - mx);
    float isum = 1.0f / sum;
    for (int d = 0; d < 24; ++d)
      attn[((size_t)bh)*576 + tid*24 + d] = __expf(sm[tid*24 + d] - mx) * isum;
  }
}

// ---------------- gate: W2 @ vmax + W3 @ vavg ----------------
__global__ void k_gate(const float* __restrict__ vmax, const float* __restrict__ vavg,
                       const float* __restrict__ w2, const float* __restrict__ w3,
                       float* __restrict__ gate){
  __shared__ float vm[192], va[192];
  int b = blockIdx.x, tid = threadIdx.x;
  if (tid < 192){ vm[tid] = vmax[b*192 + tid]; va[tid] = vavg[b*192 + tid]; }
  __syncthreads();
  if (tid < 192){
    float s = 0.f;
    const float* w2r = w2 + tid*192;
    const float* w3r = w3 + tid*192;
    for (int k = 0; k < 192; ++k) s += w2r[k]*vm[k] + w3r[k]*va[k];
    gate[b*192 + tid] = s;
  }
}

// ---------------- low branch: conv4b dw 3x3 + gate + per-head 24x24 attn apply ----------------
__global__ void k_low(const bf16* __restrict__ x4ap, const float* __restrict__ attn,
                      const float* __restrict__ gate, const float* __restrict__ w4b,
                      bf16* __restrict__ hlp){
  __shared__ bf16 xt[3*18*18*8];
  __shared__ float a2[576];
  __shared__ float wt[216];
  __shared__ float vt[24*256];
  int t = blockIdx.x, h = blockIdx.y, b = blockIdx.z, tid = threadIdx.x;
  int r0 = (t >> 4)*16, c0 = (t & 15)*16;
  int ch0 = h*24;
  for (int i = tid; i < 576; i += 256)
    a2[i] = attn[((size_t)(b*8 + h))*576 + i] * gate[b*192 + ch0 + (i % 24)];
  for (int i = tid; i < 216; i += 256) wt[i] = w4b[ch0*9 + i];
  for (int i = tid; i < 972; i += 256){
    int kb = i/324, p = i - kb*324;
    int r = p/18, c = p - r*18;
    int gr = r0 + r - 1, gc = c0 + c - 1;
    uint4 v = {0,0,0,0};
    if ((unsigned)gr < 256u && (unsigned)gc < 256u)
      v = *(const uint4*)(x4ap + (((size_t)(b*24 + h*3 + kb))*NPIX + gr*256 + gc)*8);
    *(uint4*)&xt[i*8] = v;
  }
  __syncthreads();
  {
    int r = tid >> 4, c = tid & 15;
    #pragma unroll
    for (int ch = 0; ch < 24; ++ch){
      int kb = ch >> 3, ci = ch & 7;
      float s = 0.f;
      #pragma unroll
      for (int dr = 0; dr < 3; ++dr)
        #pragma unroll
        for (int dc = 0; dc < 3; ++dc)
          s += wt[ch*9 + dr*3 + dc] *
               __bfloat162float(xt[((kb*18 + r + dr)*18 + c + dc)*8 + ci]);
      vt[ch*256 + tid] = s;
    }
  }
  __syncthreads();
  {
    float o[24];
    #pragma unroll
    for (int cc = 0; cc < 24; ++cc){
      float s = 0.f;
      #pragma unroll
      for (int d = 0; d < 24; ++d) s += a2[cc*24 + d] * vt[d*256 + tid];
      o[cc] = s;
    }
    int n = (r0 + (tid >> 4))*256 + c0 + (tid & 15);
    #pragma unroll
    for (int kb = 0; kb < 3; ++kb){
      alignas(16) bf16 c8[8];
      #pragma unroll
      for (int i = 0; i < 8; ++i) c8[i] = __float2bfloat16(o[kb*8 + i]);
      *(uint4*)(hlp + (((size_t)(b*48 + 24 + h*3 + kb))*NPIX + n)*8) = *(const uint4*)c8;
    }
  }
}

extern "C" void kernel_launch(void* const* d_in, const int* in_sizes, int n_in,
                              void* d_out, int out_size, void* d_ws, size_t ws_size,
                              hipStream_t stream){
  const float* x        = (const float*)d_in[0];
  const float* w_dww    = (const float*)d_in[1];
  const float* b_dww    = (const float*)d_in[2];
  const float* w_dwh    = (const float*)d_in[3];
  const float* b_dwh    = (const float*)d_in[4];
  const float* w_dwhw   = (const float*)d_in[5];
  const float* b_dwhw   = (const float*)d_in[6];
  const float* w_conv1  = (const float*)d_in[7];
  const float* w_qkv    = (const float*)d_in[8];
  const float* w_qkvdw  = (const float*)d_in[9];
  const float* w_conv2  = (const float*)d_in[10];
  const float* w_conv3  = (const float*)d_in[11];
  const float* w_conv4a = (const float*)d_in[12];
  const float* w_conv4b = (const float*)d_in[13];
  const float* w_proj   = (const float*)d_in[14];
  const float* temp     = (const float*)d_in[15];

  char* ws = (char*)d_ws;
  size_t off = 0;
  auto take = [&](size_t bytes)->char*{
    char* r = ws + off;
    off = (off + bytes + 255) & ~(size_t)255;
    return r;
  };
  bf16*  xp    = (bf16*) take((size_t)4*192*65536*2);  // packed x
  bf16*  hw3p  = (bf16*) take((size_t)4*384*65536*2);  // packed high pre-conv1
  bf16*  hlp   = (bf16*) take((size_t)4*384*65536*2);  // packed [high|low] proj input
  bf16*  x4ap  = (bf16*) take((size_t)4*192*65536*2);  // packed conv4a out
  bf16*  xdp   = (bf16*) take((size_t)4*192*1024*2);   // packed pooled x
  bf16*  qkv0p = (bf16*) take((size_t)4*576*1024*2);   // packed qkv 1x1 out
  float* qkvd  = (float*)take((size_t)4*576*1024*4);   // planar qkv post-dw
  float* attn  = (float*)take((size_t)4*8*576*4);
  float* vmax  = (float*)take((size_t)4*192*4);
  float* vavg  = (float*)take((size_t)4*192*4);
  float* gate  = (float*)take((size_t)4*192*4);
  bf16*  wbf   = (bf16*) take((size_t)294912*2);
  if (off > ws_size) return;  // workspace too small: fail loudly via absmax

  k_cast_w<<<1152, 256, 0, stream>>>(w_conv1, w_conv4a, w_proj, w_qkv, wbf);
  k_pack_x<<<dim3(64,24,4), 256, 0, stream>>>(x, xp);
  k_pool<<<dim3(32,24,4), 256, 0, stream>>>(xp, xdp);
  k_gemm<192,false><<<dim3(8,6,4), 256, 0, stream>>>(xdp, wbf + 184320, qkv0p, 1024, 72);
  k_qkv_dw<<<dim3(72,4), 256, 0, stream>>>(qkv0p, w_qkvdw, qkvd, vmax, vavg);
  k_attn<<<32, 256, 0, stream>>>(qkvd, temp, attn);
  k_gate<<<4, 192, 0, stream>>>(vmax, vavg, w_conv2, w_conv3, gate);
  k_high_dw<<<dim3(256,24,4), 256, 0, stream>>>(xp, w_dww, b_dww, w_dwh, b_dwh, w_dwhw, b_dwhw, hw3p);
  k_gemm<384,false><<<dim3(512,2,4), 256, 0, stream>>>(hw3p, wbf, hlp, 65536, 48);
  k_gemm<192,false><<<dim3(512,2,4), 256, 0, stream>>>(xp, wbf + 73728, x4ap, 65536, 24);
  k_low<<<dim3(256,8,4), 256, 0, stream>>>(x4ap, attn, gate, w_conv4b, hlp);
  k_gemm<384,true><<<dim3(512,2,4), 256, 0, stream>>>(hlp, wbf + 110592, d_out, 65536, 192);
}

// Round 3
// 1003.057 us; speedup vs baseline: 1.1905x; 1.0233x over previous
//
#include <hip/hip_runtime.h>
#include <hip/hip_bf16.h>

typedef __hip_bfloat16 bf16;
typedef __attribute__((ext_vector_type(8))) short s8v;
typedef __attribute__((ext_vector_type(4))) float f4;
typedef __attribute__((ext_vector_type(2))) float f2;

#define DEVI __device__ __forceinline__

DEVI f4 mfma16(s8v a, s8v b, f4 c){
  return __builtin_amdgcn_mfma_f32_16x16x32_bf16(a, b, c, 0, 0, 0);
}

constexpr int NPIX = 65536;   // 256*256
constexpr int NDOWN = 1024;   // 32*32

// ---------------- cast weights to bf16 ----------------
// layout in wbf (elements): [0) w_conv1 73728 | [73728) w_conv4a 36864 |
//                           [110592) w_proj 73728 | [184320) w_qkv 110592
__global__ void k_cast_w(const float* __restrict__ w1, const float* __restrict__ w4a,
                         const float* __restrict__ wp, const float* __restrict__ wq,
                         bf16* __restrict__ out){
  int i = blockIdx.x*256 + threadIdx.x;
  if (i < 73728) out[i] = __float2bfloat16(w1[i]);
  else if (i < 110592) out[i] = __float2bfloat16(w4a[i - 73728]);
  else if (i < 184320) out[i] = __float2bfloat16(wp[i - 110592]);
  else if (i < 294912) out[i] = __float2bfloat16(wq[i - 184320]);
}

// ---------------- pack x: fp32 planar -> bf16 K-packed [b][24][65536][8] ----------------
__global__ void k_pack_x(const float* __restrict__ x, bf16* __restrict__ xp){
  __shared__ float t[8][1032];
  int b = blockIdx.z, cb = blockIdx.y, ns = blockIdx.x, tid = threadIdx.x;
  const float* src = x + ((size_t)(b*192 + cb*8))*NPIX + ns*1024;
  #pragma unroll
  for (int i = 0; i < 8; ++i){
    float4 v = *(const float4*)(src + (size_t)i*NPIX + tid*4);
    *(float4*)&t[i][tid*4] = v;
  }
  __syncthreads();
  bf16* dst = xp + (((size_t)(b*24 + cb))*NPIX + ns*1024)*8;
  #pragma unroll
  for (int j = 0; j < 4; ++j){
    int p = j*256 + tid;
    alignas(16) bf16 c8[8];
    #pragma unroll
    for (int i = 0; i < 8; ++i) c8[i] = __float2bfloat16(t[i][p]);
    *(uint4*)(dst + (size_t)p*8) = *(const uint4*)c8;
  }
}

// ---------------- avg-pool 8x8 -> packed bf16 [b][24][1024][8] ----------------
__global__ void k_pool(const bf16* __restrict__ xp, bf16* __restrict__ xdp){
  __shared__ float red[8][32][8];
  int b = blockIdx.z, cb = blockIdx.y, hd = blockIdx.x, tid = threadIdx.x;
  int r = tid >> 5, wd = tid & 31;
  const bf16* src = xp + (((size_t)(b*24 + cb))*NPIX + (hd*8 + r)*256 + wd*8)*8;
  float acc[8] = {0,0,0,0,0,0,0,0};
  #pragma unroll
  for (int ww = 0; ww < 8; ++ww){
    uint4 raw = *(const uint4*)(src + ww*8);
    const bf16* c8 = (const bf16*)&raw;
    #pragma unroll
    for (int i = 0; i < 8; ++i) acc[i] += __bfloat162float(c8[i]);
  }
  #pragma unroll
  for (int i = 0; i < 8; ++i) red[r][wd][i] = acc[i];
  __syncthreads();
  if (tid < 32){
    alignas(16) bf16 o8[8];
    #pragma unroll
    for (int i = 0; i < 8; ++i){
      float s = 0.f;
      #pragma unroll
      for (int rr = 0; rr < 8; ++rr) s += red[rr][tid][i];
      o8[i] = __float2bfloat16(s * (1.0f/64.0f));
    }
    *(uint4*)(xdp + (((size_t)(b*24 + cb))*NDOWN + hd*32 + tid)*8) = *(const uint4*)o8;
  }
}

// ---------------- MFMA GEMM: out[b][m][n] = sum_k W[m][k] * Bp[b][k][n] ----------------
// Bp is K-packed bf16 [b][K/8][npix][8]. Block tile 96(M) x 128(N), 4 waves of 48x64.
// PLANAR=false: packed bf16 out [b][outkb][npix][8]; PLANAR=true: planar fp32, outkb=#channels.
template<int K, bool PLANAR>
__launch_bounds__(256, 2)
__global__ void k_gemm(const bf16* __restrict__ Bp, const bf16* __restrict__ W,
                       void* __restrict__ outp, int npix, int outkb){
  constexpr int KB8 = K/8;
  constexpr int NIT = K/64;
  __shared__ bf16 As[96*72];
  __shared__ bf16 Bs[128*72];
  int tid = threadIdx.x;
  int b = blockIdx.z;
  int m0 = blockIdx.y*96;
  int n0 = blockIdx.x*128;
  int wave = tid >> 6, lane = tid & 63;
  int wm = wave >> 1, wn = wave & 1;
  int lr = lane & 15, kg = lane >> 4;
  f4 acc[3][4] = {};
  const size_t bK = (size_t)b * KB8;
  for (int kt = 0; kt < NIT; ++kt){
    {
      int idx = tid;
      #pragma unroll
      for (int j = 0; j < 3; ++j, idx += 256){
        int m = idx >> 3, kc = idx & 7;
        *(uint4*)&As[m*72 + kc*8] = *(const uint4*)(W + (size_t)(m0 + m)*K + kt*64 + kc*8);
      }
      idx = tid;
      #pragma unroll
      for (int j = 0; j < 4; ++j, idx += 256){
        int kb = idx >> 7, n = idx & 127;
        *(uint4*)&Bs[n*72 + kb*8] = *(const uint4*)(Bp + ((bK + kt*8 + kb)*npix + n0 + n)*8);
      }
    }
    __syncthreads();
    #pragma unroll
    for (int kk = 0; kk < 2; ++kk){
      s8v af[3]; s8v bfr[4];
      int ko = kk*32 + kg*8;
      #pragma unroll
      for (int mf = 0; mf < 3; ++mf) af[mf] = *(const s8v*)&As[(wm*48 + mf*16 + lr)*72 + ko];
      #pragma unroll
      for (int nf = 0; nf < 4; ++nf) bfr[nf] = *(const s8v*)&Bs[(wn*64 + nf*16 + lr)*72 + ko];
      #pragma unroll
      for (int mf = 0; mf < 3; ++mf)
        #pragma unroll
        for (int nf = 0; nf < 4; ++nf)
          acc[mf][nf] = mfma16(af[mf], bfr[nf], acc[mf][nf]);
    }
    __syncthreads();
  }
  int quad = lane >> 4;
  #pragma unroll
  for (int mf = 0; mf < 3; ++mf){
    int mb = m0 + wm*48 + mf*16 + quad*4;
    #pragma unroll
    for (int nf = 0; nf < 4; ++nf){
      int n = n0 + wn*64 + nf*16 + lr;
      if constexpr (PLANAR){
        float* o = (float*)outp;
        #pragma unroll
        for (int r2 = 0; r2 < 4; ++r2)
          o[((size_t)(b*outkb + mb + r2))*npix + n] = acc[mf][nf][r2];
      } else {
        bf16* o = (bf16*)outp;
        alignas(8) bf16 v4[4];
        #pragma unroll
        for (int r2 = 0; r2 < 4; ++r2) v4[r2] = __float2bfloat16(acc[mf][nf][r2]);
        *(uint2*)(o + ((size_t)(b*outkb + (mb >> 3))*npix + n)*8 + (mb & 7)) = *(const uint2*)v4;
      }
    }
  }
}

// ---------------- high branch: strip dw convs + 3x3 dw, fused ----------------
// xp packed [b][24][65536][8] -> hw3p packed [b][48][65536][8]
// kblk 0..23 = 3x3dw(dww branch), kblk 24..47 = 3x3dw(dwh branch)
// v4: phase A writes branch-planar f32 intermediates dws[branch][ch] (plane
//     stride 364 = 4*odd mod 32, row stride 20) -> phase B reads rows via
//     b128 (bank-ideal: bases 12ch+20r cover each bank exactly 8x) and
//     slides the 3x3 window in registers; 16 scalar bf16 global stores
//     per thread (ch lanes 0..7 merge to full 16B groups per instr).
__launch_bounds__(256, 4)
__global__ void k_high_dw(const bf16* __restrict__ xp,
    const float* __restrict__ wdww, const float* __restrict__ bdww,
    const float* __restrict__ wdwh, const float* __restrict__ bdwh,
    const float* __restrict__ w3, const float* __restrict__ b3,
    bf16* __restrict__ hw3p){
  __shared__ bf16 xs[28*29*8];      // [row][col pad29][8ch]
  __shared__ float dws[2*8*364];    // [branch][ch] planes; 18 rows x stride 20
  int t = blockIdx.x, cb = blockIdx.y, b = blockIdx.z, tid = threadIdx.x;
  int r0 = (t >> 4)*16, c0 = (t & 15)*16;

  // ---- stage x tile (28x28 halo) with padded row stride, uint4 per pixel ----
  const bf16* src = xp + ((size_t)(b*24 + cb))*NPIX*8;
  for (int i = tid; i < 784; i += 256){
    int r = i/28, c = i - r*28;
    int gr = r0 + r - 6, gc = c0 + c - 6;
    uint4 v = {0,0,0,0};
    if ((unsigned)gr < 256u && (unsigned)gc < 256u)
      v = *(const uint4*)(src + ((size_t)(gr*256 + gc))*8);
    *(uint4*)&xs[(r*29 + c)*8] = v;
  }
  __syncthreads();

  // ---- phase A: strip convs via register sliding window ----
  auto strip_task = [&](int task, bool isH){
    int ch = task & 7, idx = task >> 3;
    int cg = cb*8 + ch;
    const float* wsrc = isH ? (wdww + cg*11) : (wdwh + cg*11);
    float wv[11];
    #pragma unroll
    for (int j = 0; j < 11; ++j) wv[j] = wsrc[j];
    float bias = isH ? bdww[cg] : bdwh[cg];
    int base = isH ? ((idx + 5)*29)*8 + ch : (idx + 5)*8 + ch;
    int istr = isH ? 8 : 29*8;
    float vbuf[28];
    #pragma unroll
    for (int i = 0; i < 28; ++i)
      vbuf[i] = __bfloat162float(xs[base + i*istr]);
    int fixedv = (isH ? r0 : c0) + idx - 1;
    int varb   = (isH ? c0 : r0) - 1;
    bool fok = (unsigned)fixedv < 256u;
    float out[18];
    #pragma unroll
    for (int i = 0; i < 18; ++i){
      float s = bias;
      #pragma unroll
      for (int j = 0; j < 11; ++j) s += wv[j]*vbuf[i + j];
      bool ok = fok && ((unsigned)(varb + i) < 256u);
      out[i] = ok ? s : 0.f;
    }
    if (isH){
      float* ob = &dws[ch*364 + idx*20];
      #pragma unroll
      for (int q = 0; q < 4; ++q){
        f4 v; v[0] = out[q*4]; v[1] = out[q*4+1]; v[2] = out[q*4+2]; v[3] = out[q*4+3];
        *(f4*)(ob + q*4) = v;
      }
      f2 v2; v2[0] = out[16]; v2[1] = out[17];
      *(f2*)(ob + 16) = v2;
    } else {
      float* ob = &dws[(8 + ch)*364 + idx];
      #pragma unroll
      for (int i = 0; i < 18; ++i) ob[i*20] = out[i];
    }
  };
  {
    bool isH = tid < 144;
    int task = isH ? tid : tid - 144;   // H tasks 0..143, V tasks 0..111
    strip_task(task, isH);
    if (tid >= 224) strip_task(tid - 112, false);  // V tasks 112..143
  }
  __syncthreads();

  // ---- phase B: 3x3 combine, register sliding along the row ----
  {
    int branch = tid >> 7, rr = (tid >> 3) & 15, ch = tid & 7;
    int cg = cb*8 + ch;
    const float* wsrc = w3 + (branch*192 + cg)*9;
    float w[9];
    #pragma unroll
    for (int k = 0; k < 9; ++k) w[k] = wsrc[k];
    float bias = b3[branch*192 + cg];
    float acc[16];
    #pragma unroll
    for (int i = 0; i < 16; ++i) acc[i] = bias;
    const float* plane = &dws[(branch*8 + ch)*364];
    #pragma unroll
    for (int dr = 0; dr < 3; ++dr){
      const float* rp = plane + (rr + dr)*20;
      float rowv[18];
      #pragma unroll
      for (int q = 0; q < 4; ++q){
        f4 v = *(const f4*)(rp + q*4);
        rowv[q*4] = v[0]; rowv[q*4+1] = v[1]; rowv[q*4+2] = v[2]; rowv[q*4+3] = v[3];
      }
      {
        f2 v2 = *(const f2*)(rp + 16);
        rowv[16] = v2[0]; rowv[17] = v2[1];
      }
      #pragma unroll
      for (int dc = 0; dc < 3; ++dc){
        float wv = w[dr*3 + dc];
        #pragma unroll
        for (int i = 0; i < 16; ++i) acc[i] += wv * rowv[i + dc];
      }
    }
    bf16* o = hw3p + (((size_t)(b*48 + branch*24 + cb))*NPIX + (size_t)(r0 + rr)*256 + c0)*8 + ch;
    #pragma unroll
    for (int i = 0; i < 16; ++i) o[i*8] = __float2bfloat16(acc[i]);
  }
}

// ---------------- qkv depthwise 3x3 (+ v max/avg reduction for cb>=48) ----------------
__global__ void k_qkv_dw(const bf16* __restrict__ qkv0p, const float* __restrict__ wdw,
                         float* __restrict__ qkvd, float* __restrict__ vmax, float* __restrict__ vavg){
  __shared__ bf16 xs[34*34*8];
  __shared__ float red[256*8];
  int cb = blockIdx.x, b = blockIdx.y, tid = threadIdx.x;
  for (int i = tid; i < 1156; i += 256){
    int r = i/34, c = i - r*34;
    int gr = r - 1, gc = c - 1;
    uint4 v = {0,0,0,0};
    if ((unsigned)gr < 32u && (unsigned)gc < 32u)
      v = *(const uint4*)(qkv0p + (((size_t)(b*72 + cb))*NDOWN + gr*32 + gc)*8);
    *(uint4*)&xs[i*8] = v;
  }
  __syncthreads();
  float mxv[8], smv[8];
  #pragma unroll
  for (int ch = 0; ch < 8; ++ch){ mxv[ch] = -3.4e38f; smv[ch] = 0.f; }
  for (int j = 0; j < 4; ++j){
    int p = j*256 + tid;
    int r = p >> 5, c = p & 31;
    #pragma unroll
    for (int ch = 0; ch < 8; ++ch){
      float s = 0.f;
      #pragma unroll
      for (int dr = 0; dr < 3; ++dr)
        #pragma unroll
        for (int dc = 0; dc < 3; ++dc)
          s += wdw[(cb*8 + ch)*9 + dr*3 + dc] *
               __bfloat162float(xs[((r + dr)*34 + c + dc)*8 + ch]);
      qkvd[((size_t)(b*576 + cb*8 + ch))*NDOWN + p] = s;
      mxv[ch] = fmaxf(mxv[ch], s);
      smv[ch] += s;
    }
  }
  if (cb >= 48){
    #pragma unroll
    for (int ch = 0; ch < 8; ++ch) red[tid*8 + ch] = mxv[ch];
    __syncthreads();
    for (int st = 128; st > 0; st >>= 1){
      if (tid < st)
        #pragma unroll
        for (int ch = 0; ch < 8; ++ch)
          red[tid*8 + ch] = fmaxf(red[tid*8 + ch], red[(tid + st)*8 + ch]);
      __syncthreads();
    }
    if (tid < 8) vmax[b*192 + (cb - 48)*8 + tid] = red[tid];
    __syncthreads();
    #pragma unroll
    for (int ch = 0; ch < 8; ++ch) red[tid*8 + ch] = smv[ch];
    __syncthreads();
    for (int st = 128; st > 0; st >>= 1){
      if (tid < st)
        #pragma unroll
        for (int ch = 0; ch < 8; ++ch) red[tid*8 + ch] += red[(tid + st)*8 + ch];
      __syncthreads();
    }
    if (tid < 8) vavg[b*192 + (cb - 48)*8 + tid] = red[tid] * (1.0f/1024.0f);
  }
}

// ---------------- attention matrix: normalize q,k rows; softmax(temp * q_hat k_hat^T) ----------------
__global__ void k_attn(const float* __restrict__ qkvd, const float* __restrict__ temp,
                       float* __restrict__ attn){
  __shared__ float inv[48];
  __shared__ float sm[576];
  int bh = blockIdx.x;
  int b = bh >> 3, h = bh & 7;
  const float* qb = qkvd + ((size_t)(b*576 + h*24))*NDOWN;
  const float* kb = qkvd + ((size_t)(b*576 + 192 + h*24))*NDOWN;
  int tid = threadIdx.x, wave = tid >> 6, lane = tid & 63;
  for (int v = wave; v < 48; v += 4){
    const float* p = (v < 24) ? (qb + v*NDOWN) : (kb + (v - 24)*NDOWN);
    float s = 0.f;
    for (int i = lane; i < NDOWN; i += 64){ float xv = p[i]; s += xv*xv; }
    #pragma unroll
    for (int o = 32; o > 0; o >>= 1) s += __shfl_down(s, o);
    if (lane == 0) inv[v] = 1.0f / fmaxf(sqrtf(s), 1e-12f);
  }
  __syncthreads();
  float tp = temp[h];
  for (int pr = tid; pr < 576; pr += 256){
    int c = pr/24, d = pr - c*24;
    const float4* qp = (const float4*)(qb + c*NDOWN);
    const float4* kp = (const float4*)(kb + d*NDOWN);
    float s = 0.f;
    for (int i = 0; i < 256; ++i){
      float4 a = qp[i], e = kp[i];
      s += a.x*e.x + a.y*e.y + a.z*e.z + a.w*e.w;
    }
    sm[pr] = s * inv[c] * inv[24 + d] * tp;
  }
  __syncthreads();
  if (tid < 24){
    float mx = -3.4e38f;
    for (int d = 0; d < 24; ++d) mx = fmaxf(mx, sm[tid*24 + d]);
    float sum = 0.f;
    for (int d = 0; d < 24; ++d) sum += __expf(sm[tid*24 + d] - mx);
    float isum = 1.0f / sum;
    for (int d = 0; d < 24; ++d)
      attn[((size_t)bh)*576 + tid*24 + d] = __expf(sm[tid*24 + d] - mx) * isum;
  }
}

// ---------------- gate: W2 @ vmax + W3 @ vavg ----------------
__global__ void k_gate(const float* __restrict__ vmax, const float* __restrict__ vavg,
                       const float* __restrict__ w2, const float* __restrict__ w3,
                       float* __restrict__ gate){
  __shared__ float vm[192], va[192];
  int b = blockIdx.x, tid = threadIdx.x;
  if (tid < 192){ vm[tid] = vmax[b*192 + tid]; va[tid] = vavg[b*192 + tid]; }
  __syncthreads();
  if (tid < 192){
    float s = 0.f;
    const float* w2r = w2 + tid*192;
    const float* w3r = w3 + tid*192;
    for (int k = 0; k < 192; ++k) s += w2r[k]*vm[k] + w3r[k]*va[k];
    gate[b*192 + tid] = s;
  }
}

// ---------------- low branch: conv4b dw 3x3 + gate + per-head 24x24 attn apply ----------------
// v5 of xt layout: pixel stride 10 u16 (banks ~2-way instead of 8-way on the
// 216 conv reads); staged via 4 aligned u32 writes per pixel.
__global__ void k_low(const bf16* __restrict__ x4ap, const float* __restrict__ attn,
                      const float* __restrict__ gate, const float* __restrict__ w4b,
                      bf16* __restrict__ hlp){
  __shared__ bf16 xt[3*18*18*10];
  __shared__ float a2[576];
  __shared__ float wt[216];
  __shared__ float vt[24*256];
  int t = blockIdx.x, h = blockIdx.y, b = blockIdx.z, tid = threadIdx.x;
  int r0 = (t >> 4)*16, c0 = (t & 15)*16;
  int ch0 = h*24;
  for (int i = tid; i < 576; i += 256)
    a2[i] = attn[((size_t)(b*8 + h))*576 + i] * gate[b*192 + ch0 + (i % 24)];
  for (int i = tid; i < 216; i += 256) wt[i] = w4b[ch0*9 + i];
  for (int i = tid; i < 972; i += 256){
    int kb = i/324, p = i - kb*324;
    int r = p/18, c = p - r*18;
    int gr = r0 + r - 1, gc = c0 + c - 1;
    uint4 v = {0,0,0,0};
    if ((unsigned)gr < 256u && (unsigned)gc < 256u)
      v = *(const uint4*)(x4ap + (((size_t)(b*24 + h*3 + kb))*NPIX + gr*256 + gc)*8);
    const unsigned* u = (const unsigned*)&v;
    #pragma unroll
    for (int k = 0; k < 4; ++k) *(unsigned*)&xt[i*10 + k*2] = u[k];
  }
  __syncthreads();
  {
    int r = tid >> 4, c = tid & 15;
    #pragma unroll
    for (int ch = 0; ch < 24; ++ch){
      int kb = ch >> 3, ci = ch & 7;
      float s = 0.f;
      #pragma unroll
      for (int dr = 0; dr < 3; ++dr)
        #pragma unroll
        for (int dc = 0; dc < 3; ++dc)
          s += wt[ch*9 + dr*3 + dc] *
               __bfloat162float(xt[((kb*18 + r + dr)*18 + c + dc)*10 + ci]);
      vt[ch*256 + tid] = s;
    }
  }
  __syncthreads();
  {
    float o[24];
    #pragma unroll
    for (int cc = 0; cc < 24; ++cc){
      float s = 0.f;
      #pragma unroll
      for (int d = 0; d < 24; ++d) s += a2[cc*24 + d] * vt[d*256 + tid];
      o[cc] = s;
    }
    int n = (r0 + (tid >> 4))*256 + c0 + (tid & 15);
    #pragma unroll
    for (int kb = 0; kb < 3; ++kb){
      alignas(16) bf16 c8[8];
      #pragma unroll
      for (int i = 0; i < 8; ++i) c8[i] = __float2bfloat16(o[kb*8 + i]);
      *(uint4*)(hlp + (((size_t)(b*48 + 24 + h*3 + kb))*NPIX + n)*8) = *(const uint4*)c8;
    }
  }
}

extern "C" void kernel_launch(void* const* d_in, const int* in_sizes, int n_in,
                              void* d_out, int out_size, void* d_ws, size_t ws_size,
                              hipStream_t stream){
  const float* x        = (const float*)d_in[0];
  const float* w_dww    = (const float*)d_in[1];
  const float* b_dww    = (const float*)d_in[2];
  const float* w_dwh    = (const float*)d_in[3];
  const float* b_dwh    = (const float*)d_in[4];
  const float* w_dwhw   = (const float*)d_in[5];
  const float* b_dwhw   = (const float*)d_in[6];
  const float* w_conv1  = (const float*)d_in[7];
  const float* w_qkv    = (const float*)d_in[8];
  const float* w_qkvdw  = (const float*)d_in[9];
  const float* w_conv2  = (const float*)d_in[10];
  const float* w_conv3  = (const float*)d_in[11];
  const float* w_conv4a = (const float*)d_in[12];
  const float* w_conv4b = (const float*)d_in[13];
  const float* w_proj   = (const float*)d_in[14];
  const float* temp     = (const float*)d_in[15];

  char* ws = (char*)d_ws;
  size_t off = 0;
  auto take = [&](size_t bytes)->char*{
    char* r = ws + off;
    off = (off + bytes + 255) & ~(size_t)255;
    return r;
  };
  bf16*  xp    = (bf16*) take((size_t)4*192*65536*2);  // packed x
  bf16*  hw3p  = (bf16*) take((size_t)4*384*65536*2);  // packed high pre-conv1
  bf16*  hlp   = (bf16*) take((size_t)4*384*65536*2);  // packed [high|low] proj input
  bf16*  x4ap  = (bf16*) take((size_t)4*192*65536*2);  // packed conv4a out
  bf16*  xdp   = (bf16*) take((size_t)4*192*1024*2);   // packed pooled x
  bf16*  qkv0p = (bf16*) take((size_t)4*576*1024*2);   // packed qkv 1x1 out
  float* qkvd  = (float*)take((size_t)4*576*1024*4);   // planar qkv post-dw
  float* attn  = (float*)take((size_t)4*8*576*4);
  float* vmax  = (float*)take((size_t)4*192*4);
  float* vavg  = (float*)take((size_t)4*192*4);
  float* gate  = (float*)take((size_t)4*192*4);
  bf16*  wbf   = (bf16*) take((size_t)294912*2);
  if (off > ws_size) return;  // workspace too small: fail loudly via absmax

  k_cast_w<<<1152, 256, 0, stream>>>(w_conv1, w_conv4a, w_proj, w_qkv, wbf);
  k_pack_x<<<dim3(64,24,4), 256, 0, stream>>>(x, xp);
  k_pool<<<dim3(32,24,4), 256, 0, stream>>>(xp, xdp);
  k_gemm<192,false><<<dim3(8,6,4), 256, 0, stream>>>(xdp, wbf + 184320, qkv0p, 1024, 72);
  k_qkv_dw<<<dim3(72,4), 256, 0, stream>>>(qkv0p, w_qkvdw, qkvd, vmax, vavg);
  k_attn<<<32, 256, 0, stream>>>(qkvd, temp, attn);
  k_gate<<<4, 192, 0, stream>>>(vmax, vavg, w_conv2, w_conv3, gate);
  k_high_dw<<<dim3(256,24,4), 256, 0, stream>>>(xp, w_dww, b_dww, w_dwh, b_dwh, w_dwhw, b_dwhw, hw3p);
  k_gemm<384,false><<<dim3(512,2,4), 256, 0, stream>>>(hw3p, wbf, hlp, 65536, 48);
  k_gemm<192,false><<<dim3(512,2,4), 256, 0, stream>>>(xp, wbf + 73728, x4ap, 65536, 24);
  k_low<<<dim3(256,8,4), 256, 0, stream>>>(x4ap, attn, gate, w_conv4b, hlp);
  k_gemm<384,true><<<dim3(512,2,4), 256, 0, stream>>>(hlp, wbf + 110592, d_out, 65536, 192);
}

// Round 4
// 922.930 us; speedup vs baseline: 1.2939x; 1.0868x over previous
//
#include <hip/hip_runtime.h>
#include <hip/hip_bf16.h>

typedef __hip_bfloat16 bf16;
typedef __attribute__((ext_vector_type(8))) short s8v;
typedef __attribute__((ext_vector_type(4))) float f4;
typedef __attribute__((ext_vector_type(2))) float f2;

#define DEVI __device__ __forceinline__

DEVI f4 mfma16(s8v a, s8v b, f4 c){
  return __builtin_amdgcn_mfma_f32_16x16x32_bf16(a, b, c, 0, 0, 0);
}

constexpr int NPIX = 65536;   // 256*256
constexpr int NDOWN = 1024;   // 32*32

// ---------------- cast weights to bf16 ----------------
// layout in wbf (elements): [0) w_conv1 73728 | [73728) w_conv4a 36864 |
//                           [110592) w_proj 73728 | [184320) w_qkv 110592
__global__ void k_cast_w(const float* __restrict__ w1, const float* __restrict__ w4a,
                         const float* __restrict__ wp, const float* __restrict__ wq,
                         bf16* __restrict__ out){
  int i = blockIdx.x*256 + threadIdx.x;
  if (i < 73728) out[i] = __float2bfloat16(w1[i]);
  else if (i < 110592) out[i] = __float2bfloat16(w4a[i - 73728]);
  else if (i < 184320) out[i] = __float2bfloat16(wp[i - 110592]);
  else if (i < 294912) out[i] = __float2bfloat16(wq[i - 184320]);
}

// ---------------- pack x: fp32 planar -> bf16 K-packed [b][24][65536][8] ----------------
__global__ void k_pack_x(const float* __restrict__ x, bf16* __restrict__ xp){
  __shared__ float t[8][1032];
  int b = blockIdx.z, cb = blockIdx.y, ns = blockIdx.x, tid = threadIdx.x;
  const float* src = x + ((size_t)(b*192 + cb*8))*NPIX + ns*1024;
  #pragma unroll
  for (int i = 0; i < 8; ++i){
    float4 v = *(const float4*)(src + (size_t)i*NPIX + tid*4);
    *(float4*)&t[i][tid*4] = v;
  }
  __syncthreads();
  bf16* dst = xp + (((size_t)(b*24 + cb))*NPIX + ns*1024)*8;
  #pragma unroll
  for (int j = 0; j < 4; ++j){
    int p = j*256 + tid;
    alignas(16) bf16 c8[8];
    #pragma unroll
    for (int i = 0; i < 8; ++i) c8[i] = __float2bfloat16(t[i][p]);
    *(uint4*)(dst + (size_t)p*8) = *(const uint4*)c8;
  }
}

// ---------------- avg-pool 8x8 -> packed bf16 [b][24][1024][8] ----------------
__global__ void k_pool(const bf16* __restrict__ xp, bf16* __restrict__ xdp){
  __shared__ float red[8][32][8];
  int b = blockIdx.z, cb = blockIdx.y, hd = blockIdx.x, tid = threadIdx.x;
  int r = tid >> 5, wd = tid & 31;
  const bf16* src = xp + (((size_t)(b*24 + cb))*NPIX + (hd*8 + r)*256 + wd*8)*8;
  float acc[8] = {0,0,0,0,0,0,0,0};
  #pragma unroll
  for (int ww = 0; ww < 8; ++ww){
    uint4 raw = *(const uint4*)(src + ww*8);
    const bf16* c8 = (const bf16*)&raw;
    #pragma unroll
    for (int i = 0; i < 8; ++i) acc[i] += __bfloat162float(c8[i]);
  }
  #pragma unroll
  for (int i = 0; i < 8; ++i) red[r][wd][i] = acc[i];
  __syncthreads();
  if (tid < 32){
    alignas(16) bf16 o8[8];
    #pragma unroll
    for (int i = 0; i < 8; ++i){
      float s = 0.f;
      #pragma unroll
      for (int rr = 0; rr < 8; ++rr) s += red[rr][tid][i];
      o8[i] = __float2bfloat16(s * (1.0f/64.0f));
    }
    *(uint4*)(xdp + (((size_t)(b*24 + cb))*NDOWN + hd*32 + tid)*8) = *(const uint4*)o8;
  }
}

// ---------------- MFMA GEMM: out[b][m][n] = sum_k W[m][k] * Bp[b][k][n] ----------------
// Bp is K-packed bf16 [b][K/8][npix][8]. Block tile 96(M) x 128(N), 4 waves of 48x64.
// PLANAR=false: packed bf16 out [b][outkb][npix][8]; PLANAR=true: planar fp32, outkb=#channels.
// wstride: per-batch W stride in elements (0 = shared weights).
template<int K, bool PLANAR>
__launch_bounds__(256, 2)
__global__ void k_gemm(const bf16* __restrict__ Bp, const bf16* __restrict__ W,
                       void* __restrict__ outp, int npix, int outkb, unsigned wstride){
  constexpr int KB8 = K/8;
  constexpr int NIT = K/64;
  __shared__ bf16 As[96*72];
  __shared__ bf16 Bs[128*72];
  int tid = threadIdx.x;
  int b = blockIdx.z;
  int m0 = blockIdx.y*96;
  int n0 = blockIdx.x*128;
  W += (size_t)b * wstride;
  int wave = tid >> 6, lane = tid & 63;
  int wm = wave >> 1, wn = wave & 1;
  int lr = lane & 15, kg = lane >> 4;
  f4 acc[3][4] = {};
  const size_t bK = (size_t)b * KB8;
  for (int kt = 0; kt < NIT; ++kt){
    {
      int idx = tid;
      #pragma unroll
      for (int j = 0; j < 3; ++j, idx += 256){
        int m = idx >> 3, kc = idx & 7;
        *(uint4*)&As[m*72 + kc*8] = *(const uint4*)(W + (size_t)(m0 + m)*K + kt*64 + kc*8);
      }
      idx = tid;
      #pragma unroll
      for (int j = 0; j < 4; ++j, idx += 256){
        int kb = idx >> 7, n = idx & 127;
        *(uint4*)&Bs[n*72 + kb*8] = *(const uint4*)(Bp + ((bK + kt*8 + kb)*npix + n0 + n)*8);
      }
    }
    __syncthreads();
    #pragma unroll
    for (int kk = 0; kk < 2; ++kk){
      s8v af[3]; s8v bfr[4];
      int ko = kk*32 + kg*8;
      #pragma unroll
      for (int mf = 0; mf < 3; ++mf) af[mf] = *(const s8v*)&As[(wm*48 + mf*16 + lr)*72 + ko];
      #pragma unroll
      for (int nf = 0; nf < 4; ++nf) bfr[nf] = *(const s8v*)&Bs[(wn*64 + nf*16 + lr)*72 + ko];
      #pragma unroll
      for (int mf = 0; mf < 3; ++mf)
        #pragma unroll
        for (int nf = 0; nf < 4; ++nf)
          acc[mf][nf] = mfma16(af[mf], bfr[nf], acc[mf][nf]);
    }
    __syncthreads();
  }
  int quad = lane >> 4;
  #pragma unroll
  for (int mf = 0; mf < 3; ++mf){
    int mb = m0 + wm*48 + mf*16 + quad*4;
    #pragma unroll
    for (int nf = 0; nf < 4; ++nf){
      int n = n0 + wn*64 + nf*16 + lr;
      if constexpr (PLANAR){
        float* o = (float*)outp;
        #pragma unroll
        for (int r2 = 0; r2 < 4; ++r2)
          o[((size_t)(b*outkb + mb + r2))*npix + n] = acc[mf][nf][r2];
      } else {
        bf16* o = (bf16*)outp;
        alignas(8) bf16 v4[4];
        #pragma unroll
        for (int r2 = 0; r2 < 4; ++r2) v4[r2] = __float2bfloat16(acc[mf][nf][r2]);
        *(uint2*)(o + ((size_t)(b*outkb + (mb >> 3))*npix + n)*8 + (mb & 7)) = *(const uint2*)v4;
      }
    }
  }
}

// ---------------- high branch: strip dw convs + 3x3 dw, fused ----------------
// xp packed [b][24][65536][8] -> hw3p packed [b][48][65536][8]
// kblk 0..23 = 3x3dw(dww branch), kblk 24..47 = 3x3dw(dwh branch)
__launch_bounds__(256, 4)
__global__ void k_high_dw(const bf16* __restrict__ xp,
    const float* __restrict__ wdww, const float* __restrict__ bdww,
    const float* __restrict__ wdwh, const float* __restrict__ bdwh,
    const float* __restrict__ w3, const float* __restrict__ b3,
    bf16* __restrict__ hw3p){
  __shared__ bf16 xs[28*29*8];      // [row][col pad29][8ch]
  __shared__ float dws[2*8*364];    // [branch][ch] planes; 18 rows x stride 20
  int t = blockIdx.x, cb = blockIdx.y, b = blockIdx.z, tid = threadIdx.x;
  int r0 = (t >> 4)*16, c0 = (t & 15)*16;

  // ---- stage x tile (28x28 halo) with padded row stride, uint4 per pixel ----
  const bf16* src = xp + ((size_t)(b*24 + cb))*NPIX*8;
  for (int i = tid; i < 784; i += 256){
    int r = i/28, c = i - r*28;
    int gr = r0 + r - 6, gc = c0 + c - 6;
    uint4 v = {0,0,0,0};
    if ((unsigned)gr < 256u && (unsigned)gc < 256u)
      v = *(const uint4*)(src + ((size_t)(gr*256 + gc))*8);
    *(uint4*)&xs[(r*29 + c)*8] = v;
  }
  __syncthreads();

  // ---- phase A: strip convs via register sliding window ----
  auto strip_task = [&](int task, bool isH){
    int ch = task & 7, idx = task >> 3;
    int cg = cb*8 + ch;
    const float* wsrc = isH ? (wdww + cg*11) : (wdwh + cg*11);
    float wv[11];
    #pragma unroll
    for (int j = 0; j < 11; ++j) wv[j] = wsrc[j];
    float bias = isH ? bdww[cg] : bdwh[cg];
    int base = isH ? ((idx + 5)*29)*8 + ch : (idx + 5)*8 + ch;
    int istr = isH ? 8 : 29*8;
    float vbuf[28];
    #pragma unroll
    for (int i = 0; i < 28; ++i)
      vbuf[i] = __bfloat162float(xs[base + i*istr]);
    int fixedv = (isH ? r0 : c0) + idx - 1;
    int varb   = (isH ? c0 : r0) - 1;
    bool fok = (unsigned)fixedv < 256u;
    float out[18];
    #pragma unroll
    for (int i = 0; i < 18; ++i){
      float s = bias;
      #pragma unroll
      for (int j = 0; j < 11; ++j) s += wv[j]*vbuf[i + j];
      bool ok = fok && ((unsigned)(varb + i) < 256u);
      out[i] = ok ? s : 0.f;
    }
    if (isH){
      float* ob = &dws[ch*364 + idx*20];
      #pragma unroll
      for (int q = 0; q < 4; ++q){
        f4 v; v[0] = out[q*4]; v[1] = out[q*4+1]; v[2] = out[q*4+2]; v[3] = out[q*4+3];
        *(f4*)(ob + q*4) = v;
      }
      f2 v2; v2[0] = out[16]; v2[1] = out[17];
      *(f2*)(ob + 16) = v2;
    } else {
      float* ob = &dws[(8 + ch)*364 + idx];
      #pragma unroll
      for (int i = 0; i < 18; ++i) ob[i*20] = out[i];
    }
  };
  {
    bool isH = tid < 144;
    int task = isH ? tid : tid - 144;   // H tasks 0..143, V tasks 0..111
    strip_task(task, isH);
    if (tid >= 224) strip_task(tid - 112, false);  // V tasks 112..143
  }
  __syncthreads();

  // ---- phase B: 3x3 combine, register sliding along the row ----
  {
    int branch = tid >> 7, rr = (tid >> 3) & 15, ch = tid & 7;
    int cg = cb*8 + ch;
    const float* wsrc = w3 + (branch*192 + cg)*9;
    float w[9];
    #pragma unroll
    for (int k = 0; k < 9; ++k) w[k] = wsrc[k];
    float bias = b3[branch*192 + cg];
    float acc[16];
    #pragma unroll
    for (int i = 0; i < 16; ++i) acc[i] = bias;
    const float* plane = &dws[(branch*8 + ch)*364];
    #pragma unroll
    for (int dr = 0; dr < 3; ++dr){
      const float* rp = plane + (rr + dr)*20;
      float rowv[18];
      #pragma unroll
      for (int q = 0; q < 4; ++q){
        f4 v = *(const f4*)(rp + q*4);
        rowv[q*4] = v[0]; rowv[q*4+1] = v[1]; rowv[q*4+2] = v[2]; rowv[q*4+3] = v[3];
      }
      {
        f2 v2 = *(const f2*)(rp + 16);
        rowv[16] = v2[0]; rowv[17] = v2[1];
      }
      #pragma unroll
      for (int dc = 0; dc < 3; ++dc){
        float wv = w[dr*3 + dc];
        #pragma unroll
        for (int i = 0; i < 16; ++i) acc[i] += wv * rowv[i + dc];
      }
    }
    bf16* o = hw3p + (((size_t)(b*48 + branch*24 + cb))*NPIX + (size_t)(r0 + rr)*256 + c0)*8 + ch;
    #pragma unroll
    for (int i = 0; i < 16; ++i) o[i*8] = __float2bfloat16(acc[i]);
  }
}

// ---------------- qkv depthwise 3x3 (+ v max/avg reduction for cb>=48) ----------------
__global__ void k_qkv_dw(const bf16* __restrict__ qkv0p, const float* __restrict__ wdw,
                         float* __restrict__ qkvd, float* __restrict__ vmax, float* __restrict__ vavg){
  __shared__ bf16 xs[34*34*8];
  __shared__ float red[256*8];
  int cb = blockIdx.x, b = blockIdx.y, tid = threadIdx.x;
  for (int i = tid; i < 1156; i += 256){
    int r = i/34, c = i - r*34;
    int gr = r - 1, gc = c - 1;
    uint4 v = {0,0,0,0};
    if ((unsigned)gr < 32u && (unsigned)gc < 32u)
      v = *(const uint4*)(qkv0p + (((size_t)(b*72 + cb))*NDOWN + gr*32 + gc)*8);
    *(uint4*)&xs[i*8] = v;
  }
  __syncthreads();
  float mxv[8], smv[8];
  #pragma unroll
  for (int ch = 0; ch < 8; ++ch){ mxv[ch] = -3.4e38f; smv[ch] = 0.f; }
  for (int j = 0; j < 4; ++j){
    int p = j*256 + tid;
    int r = p >> 5, c = p & 31;
    #pragma unroll
    for (int ch = 0; ch < 8; ++ch){
      float s = 0.f;
      #pragma unroll
      for (int dr = 0; dr < 3; ++dr)
        #pragma unroll
        for (int dc = 0; dc < 3; ++dc)
          s += wdw[(cb*8 + ch)*9 + dr*3 + dc] *
               __bfloat162float(xs[((r + dr)*34 + c + dc)*8 + ch]);
      qkvd[((size_t)(b*576 + cb*8 + ch))*NDOWN + p] = s;
      mxv[ch] = fmaxf(mxv[ch], s);
      smv[ch] += s;
    }
  }
  if (cb >= 48){
    #pragma unroll
    for (int ch = 0; ch < 8; ++ch) red[tid*8 + ch] = mxv[ch];
    __syncthreads();
    for (int st = 128; st > 0; st >>= 1){
      if (tid < st)
        #pragma unroll
        for (int ch = 0; ch < 8; ++ch)
          red[tid*8 + ch] = fmaxf(red[tid*8 + ch], red[(tid + st)*8 + ch]);
      __syncthreads();
    }
    if (tid < 8) vmax[b*192 + (cb - 48)*8 + tid] = red[tid];
    __syncthreads();
    #pragma unroll
    for (int ch = 0; ch < 8; ++ch) red[tid*8 + ch] = smv[ch];
    __syncthreads();
    for (int st = 128; st > 0; st >>= 1){
      if (tid < st)
        #pragma unroll
        for (int ch = 0; ch < 8; ++ch) red[tid*8 + ch] += red[(tid + st)*8 + ch];
      __syncthreads();
    }
    if (tid < 8) vavg[b*192 + (cb - 48)*8 + tid] = red[tid] * (1.0f/1024.0f);
  }
}

// ---------------- attention matrix: normalize q,k rows; softmax(temp * q_hat k_hat^T) ----------------
__global__ void k_attn(const float* __restrict__ qkvd, const float* __restrict__ temp,
                       float* __restrict__ attn){
  __shared__ float inv[48];
  __shared__ float sm[576];
  int bh = blockIdx.x;
  int b = bh >> 3, h = bh & 7;
  const float* qb = qkvd + ((size_t)(b*576 + h*24))*NDOWN;
  const float* kb = qkvd + ((size_t)(b*576 + 192 + h*24))*NDOWN;
  int tid = threadIdx.x, wave = tid >> 6, lane = tid & 63;
  for (int v = wave; v < 48; v += 4){
    const float* p = (v < 24) ? (qb + v*NDOWN) : (kb + (v - 24)*NDOWN);
    float s = 0.f;
    for (int i = lane; i < NDOWN; i += 64){ float xv = p[i]; s += xv*xv; }
    #pragma unroll
    for (int o = 32; o > 0; o >>= 1) s += __shfl_down(s, o);
    if (lane == 0) inv[v] = 1.0f / fmaxf(sqrtf(s), 1e-12f);
  }
  __syncthreads();
  float tp = temp[h];
  for (int pr = tid; pr < 576; pr += 256){
    int c = pr/24, d = pr - c*24;
    const float4* qp = (const float4*)(qb + c*NDOWN);
    const float4* kp = (const float4*)(kb + d*NDOWN);
    float s = 0.f;
    for (int i = 0; i < 256; ++i){
      float4 a = qp[i], e = kp[i];
      s += a.x*e.x + a.y*e.y + a.z*e.z + a.w*e.w;
    }
    sm[pr] = s * inv[c] * inv[24 + d] * tp;
  }
  __syncthreads();
  if (tid < 24){
    float mx = -3.4e38f;
    for (int d = 0; d < 24; ++d) mx = fmaxf(mx, sm[tid*24 + d]);
    float sum = 0.f;
    for (int d = 0; d < 24; ++d) sum += __expf(sm[tid*24 + d] - mx);
    float isum = 1.0f / sum;
    for (int d = 0; d < 24; ++d)
      attn[((size_t)bh)*576 + tid*24 + d] = __expf(sm[tid*24 + d] - mx) * isum;
  }
}

// ---------------- gate: W2 @ vmax + W3 @ vavg ----------------
__global__ void k_gate(const float* __restrict__ vmax, const float* __restrict__ vavg,
                       const float* __restrict__ w2, const float* __restrict__ w3,
                       float* __restrict__ gate){
  __shared__ float vm[192], va[192];
  int b = blockIdx.x, tid = threadIdx.x;
  if (tid < 192){ vm[tid] = vmax[b*192 + tid]; va[tid] = vavg[b*192 + tid]; }
  __syncthreads();
  if (tid < 192){
    float s = 0.f;
    const float* w2r = w2 + tid*192;
    const float* w3r = w3 + tid*192;
    for (int k = 0; k < 192; ++k) s += w2r[k]*vm[k] + w3r[k]*va[k];
    gate[b*192 + tid] = s;
  }
}

// ---------------- effective low-branch weights ----------------
// out_low = Wp_low @ (attn @ (gate .* x4))  ==  Weff_b @ x4 with
// Weff[b][o][d] = gate[b,d] * sum_cl Wp[o, 192+h*24+cl] * A[b,h,cl,dl],  h=d/24, dl=d%24.
// wfin[b] is the full per-batch [192][384] bf16 weight for the final GEMM:
// cols 0..191 = Wp high half (batch-independent), cols 192..383 = Weff.
// grid 32 = (b,h); 192 threads = o.
__global__ void k_weff(const float* __restrict__ attn, const float* __restrict__ gate,
                       const float* __restrict__ wp, bf16* __restrict__ wfin){
  __shared__ float A_s[576];
  int bh = blockIdx.x; int b = bh >> 3, h = bh & 7;
  int o = threadIdx.x;
  for (int i = o; i < 576; i += 192) A_s[i] = attn[(size_t)bh*576 + i];
  __syncthreads();
  const float* wrow = wp + (size_t)o*384;
  float wl[24];
  #pragma unroll
  for (int j = 0; j < 24; ++j) wl[j] = wrow[192 + h*24 + j];
  bf16* dst = wfin + ((size_t)b*192 + o)*384;
  #pragma unroll
  for (int j = 0; j < 24; ++j) dst[h*24 + j] = __float2bfloat16(wrow[h*24 + j]);
  #pragma unroll
  for (int dl = 0; dl < 24; ++dl){
    float s = 0.f;
    #pragma unroll
    for (int cl = 0; cl < 24; ++cl) s += wl[cl]*A_s[cl*24 + dl];
    dst[192 + h*24 + dl] = __float2bfloat16(s * gate[b*192 + h*24 + dl]);
  }
}

// ---------------- x4: depthwise 3x3 of conv4a output, packed->packed ----------------
// Replaces k_low's conv phase; attn-apply + gate folded into wfin (k_weff).
// Per-tap ds_read_b128 (conflict-free: dword starts (8r+4c)%32, 8 dwords/bank).
__global__ void k_x4(const bf16* __restrict__ x4ap, const float* __restrict__ w4b,
                     bf16* __restrict__ hlp){
  __shared__ bf16 xt[324*8];   // 18x18 halo, packed 8ch, stride 8 (16B aligned)
  __shared__ float wl4[72];
  int t = blockIdx.x, cb = blockIdx.y, b = blockIdx.z, tid = threadIdx.x;
  int r0 = (t >> 4)*16, c0 = (t & 15)*16;
  if (tid < 72) wl4[tid] = w4b[cb*72 + tid];
  for (int i = tid; i < 324; i += 256){
    int r = i/18, c = i - r*18;
    int gr = r0 + r - 1, gc = c0 + c - 1;
    uint4 v = {0,0,0,0};
    if ((unsigned)gr < 256u && (unsigned)gc < 256u)
      v = *(const uint4*)(x4ap + (((size_t)(b*24 + cb))*NPIX + gr*256 + gc)*8);
    *(uint4*)&xt[i*8] = v;
  }
  __syncthreads();
  {
    int r = tid >> 4, c = tid & 15;
    float acc[8] = {0,0,0,0,0,0,0,0};
    #pragma unroll
    for (int dr = 0; dr < 3; ++dr)
      #pragma unroll
      for (int dc = 0; dc < 3; ++dc){
        uint4 v = *(const uint4*)&xt[((r + dr)*18 + c + dc)*8];
        const bf16* c8 = (const bf16*)&v;
        int tap = dr*3 + dc;
        #pragma unroll
        for (int ch = 0; ch < 8; ++ch)
          acc[ch] += wl4[ch*9 + tap] * __bfloat162float(c8[ch]);
      }
    int n = (r0 + r)*256 + c0 + c;
    alignas(16) bf16 o8[8];
    #pragma unroll
    for (int ch = 0; ch < 8; ++ch) o8[ch] = __float2bfloat16(acc[ch]);
    *(uint4*)(hlp + (((size_t)(b*48 + 24 + cb))*NPIX + n)*8) = *(const uint4*)o8;
  }
}

extern "C" void kernel_launch(void* const* d_in, const int* in_sizes, int n_in,
                              void* d_out, int out_size, void* d_ws, size_t ws_size,
                              hipStream_t stream){
  const float* x        = (const float*)d_in[0];
  const float* w_dww    = (const float*)d_in[1];
  const float* b_dww    = (const float*)d_in[2];
  const float* w_dwh    = (const float*)d_in[3];
  const float* b_dwh    = (const float*)d_in[4];
  const float* w_dwhw   = (const float*)d_in[5];
  const float* b_dwhw   = (const float*)d_in[6];
  const float* w_conv1  = (const float*)d_in[7];
  const float* w_qkv    = (const float*)d_in[8];
  const float* w_qkvdw  = (const float*)d_in[9];
  const float* w_conv2  = (const float*)d_in[10];
  const float* w_conv3  = (const float*)d_in[11];
  const float* w_conv4a = (const float*)d_in[12];
  const float* w_conv4b = (const float*)d_in[13];
  const float* w_proj   = (const float*)d_in[14];
  const float* temp     = (const float*)d_in[15];

  char* ws = (char*)d_ws;
  size_t off = 0;
  auto take = [&](size_t bytes)->char*{
    char* r = ws + off;
    off = (off + bytes + 255) & ~(size_t)255;
    return r;
  };
  bf16*  xp    = (bf16*) take((size_t)4*192*65536*2);  // packed x
  bf16*  hw3p  = (bf16*) take((size_t)4*384*65536*2);  // packed high pre-conv1
  bf16*  hlp   = (bf16*) take((size_t)4*384*65536*2);  // packed [high|x4] proj input
  bf16*  x4ap  = (bf16*) take((size_t)4*192*65536*2);  // packed conv4a out
  bf16*  xdp   = (bf16*) take((size_t)4*192*1024*2);   // packed pooled x
  bf16*  qkv0p = (bf16*) take((size_t)4*576*1024*2);   // packed qkv 1x1 out
  float* qkvd  = (float*)take((size_t)4*576*1024*4);   // planar qkv post-dw
  float* attn  = (float*)take((size_t)4*8*576*4);
  float* vmax  = (float*)take((size_t)4*192*4);
  float* vavg  = (float*)take((size_t)4*192*4);
  float* gate  = (float*)take((size_t)4*192*4);
  bf16*  wbf   = (bf16*) take((size_t)294912*2);
  bf16*  wfin  = (bf16*) take((size_t)4*73728*2);      // per-batch final GEMM weights
  if (off > ws_size) return;  // workspace too small: fail loudly via absmax

  k_cast_w<<<1152, 256, 0, stream>>>(w_conv1, w_conv4a, w_proj, w_qkv, wbf);
  k_pack_x<<<dim3(64,24,4), 256, 0, stream>>>(x, xp);
  k_pool<<<dim3(32,24,4), 256, 0, stream>>>(xp, xdp);
  k_gemm<192,false><<<dim3(8,6,4), 256, 0, stream>>>(xdp, wbf + 184320, qkv0p, 1024, 72, 0);
  k_qkv_dw<<<dim3(72,4), 256, 0, stream>>>(qkv0p, w_qkvdw, qkvd, vmax, vavg);
  k_attn<<<32, 256, 0, stream>>>(qkvd, temp, attn);
  k_gate<<<4, 192, 0, stream>>>(vmax, vavg, w_conv2, w_conv3, gate);
  k_weff<<<32, 192, 0, stream>>>(attn, gate, w_proj, wfin);
  k_high_dw<<<dim3(256,24,4), 256, 0, stream>>>(xp, w_dww, b_dww, w_dwh, b_dwh, w_dwhw, b_dwhw, hw3p);
  k_gemm<384,false><<<dim3(512,2,4), 256, 0, stream>>>(hw3p, wbf, hlp, 65536, 48, 0);
  k_gemm<192,false><<<dim3(512,2,4), 256, 0, stream>>>(xp, wbf + 73728, x4ap, 65536, 24, 0);
  k_x4<<<dim3(256,24,4), 256, 0, stream>>>(x4ap, w_conv4b, hlp);
  k_gemm<384,true><<<dim3(512,2,4), 256, 0, stream>>>(hlp, wfin, d_out, 65536, 192, 73728);
}

// Round 5
// 910.977 us; speedup vs baseline: 1.3108x; 1.0131x over previous
//
#include <hip/hip_runtime.h>
#include <hip/hip_bf16.h>

typedef __hip_bfloat16 bf16;
typedef __attribute__((ext_vector_type(8))) short s8v;
typedef __attribute__((ext_vector_type(4))) float f4;
typedef __attribute__((ext_vector_type(2))) float f2;

#define DEVI __device__ __forceinline__

DEVI f4 mfma16(s8v a, s8v b, f4 c){
  return __builtin_amdgcn_mfma_f32_16x16x32_bf16(a, b, c, 0, 0, 0);
}

constexpr int NPIX = 65536;   // 256*256
constexpr int NDOWN = 1024;   // 32*32

// ---------------- cast weights to bf16 ----------------
// layout in wbf (elements): [0) w_conv1 73728 | [73728) w_conv4a 36864 |
//                           [110592) w_proj 73728 | [184320) w_qkv 110592
__global__ void k_cast_w(const float* __restrict__ w1, const float* __restrict__ w4a,
                         const float* __restrict__ wp, const float* __restrict__ wq,
                         bf16* __restrict__ out){
  int i = blockIdx.x*256 + threadIdx.x;
  if (i < 73728) out[i] = __float2bfloat16(w1[i]);
  else if (i < 110592) out[i] = __float2bfloat16(w4a[i - 73728]);
  else if (i < 184320) out[i] = __float2bfloat16(wp[i - 110592]);
  else if (i < 294912) out[i] = __float2bfloat16(wq[i - 184320]);
}

// ---------------- pack x: fp32 planar -> bf16 K-packed [b][24][65536][8] ----------------
__global__ void k_pack_x(const float* __restrict__ x, bf16* __restrict__ xp){
  __shared__ float t[8][1032];
  int b = blockIdx.z, cb = blockIdx.y, ns = blockIdx.x, tid = threadIdx.x;
  const float* src = x + ((size_t)(b*192 + cb*8))*NPIX + ns*1024;
  #pragma unroll
  for (int i = 0; i < 8; ++i){
    float4 v = *(const float4*)(src + (size_t)i*NPIX + tid*4);
    *(float4*)&t[i][tid*4] = v;
  }
  __syncthreads();
  bf16* dst = xp + (((size_t)(b*24 + cb))*NPIX + ns*1024)*8;
  #pragma unroll
  for (int j = 0; j < 4; ++j){
    int p = j*256 + tid;
    alignas(16) bf16 c8[8];
    #pragma unroll
    for (int i = 0; i < 8; ++i) c8[i] = __float2bfloat16(t[i][p]);
    *(uint4*)(dst + (size_t)p*8) = *(const uint4*)c8;
  }
}

// ---------------- avg-pool 8x8 -> packed bf16 [b][24][1024][8] ----------------
__global__ void k_pool(const bf16* __restrict__ xp, bf16* __restrict__ xdp){
  __shared__ float red[8][32][8];
  int b = blockIdx.z, cb = blockIdx.y, hd = blockIdx.x, tid = threadIdx.x;
  int r = tid >> 5, wd = tid & 31;
  const bf16* src = xp + (((size_t)(b*24 + cb))*NPIX + (hd*8 + r)*256 + wd*8)*8;
  float acc[8] = {0,0,0,0,0,0,0,0};
  #pragma unroll
  for (int ww = 0; ww < 8; ++ww){
    uint4 raw = *(const uint4*)(src + ww*8);
    const bf16* c8 = (const bf16*)&raw;
    #pragma unroll
    for (int i = 0; i < 8; ++i) acc[i] += __bfloat162float(c8[i]);
  }
  #pragma unroll
  for (int i = 0; i < 8; ++i) red[r][wd][i] = acc[i];
  __syncthreads();
  if (tid < 32){
    alignas(16) bf16 o8[8];
    #pragma unroll
    for (int i = 0; i < 8; ++i){
      float s = 0.f;
      #pragma unroll
      for (int rr = 0; rr < 8; ++rr) s += red[rr][tid][i];
      o8[i] = __float2bfloat16(s * (1.0f/64.0f));
    }
    *(uint4*)(xdp + (((size_t)(b*24 + cb))*NDOWN + hd*32 + tid)*8) = *(const uint4*)o8;
  }
}

// ---------------- MFMA GEMM: out[b][m][n] = sum_k W[m][k] * Bp[b][k][n] ----------------
// Bp is K-packed bf16 [b][K/8][npix][8]. Block tile 192(M) x 128(N): B is fetched
// from HBM exactly ONCE (v6; the old 96-tile grid.y=2 read every B tile twice).
// 4 waves stacked along M (48 rows each), acc[3][8].
// PLANAR=false: packed bf16 out [b][outkb][npix][8]; PLANAR=true: planar fp32.
// wstride: per-batch W stride in elements (0 = shared weights).
template<int K, bool PLANAR>
__launch_bounds__(256, 2)
__global__ void k_gemm(const bf16* __restrict__ Bp, const bf16* __restrict__ W,
                       void* __restrict__ outp, int npix, int outkb, unsigned wstride){
  constexpr int KB8 = K/8;
  constexpr int NIT = K/64;
  __shared__ bf16 As[192*72];
  __shared__ bf16 Bs[128*72];
  int tid = threadIdx.x;
  int b = blockIdx.z;
  int m0 = blockIdx.y*192;
  int n0 = blockIdx.x*128;
  W += (size_t)b * wstride;
  int wave = tid >> 6, lane = tid & 63;
  int wm = wave;
  int lr = lane & 15, kg = lane >> 4;
  f4 acc[3][8] = {};
  const size_t bK = (size_t)b * KB8;
  for (int kt = 0; kt < NIT; ++kt){
    {
      int idx = tid;
      #pragma unroll
      for (int j = 0; j < 6; ++j, idx += 256){
        int m = idx >> 3, kc = idx & 7;
        *(uint4*)&As[m*72 + kc*8] = *(const uint4*)(W + (size_t)(m0 + m)*K + kt*64 + kc*8);
      }
      idx = tid;
      #pragma unroll
      for (int j = 0; j < 4; ++j, idx += 256){
        int kb = idx >> 7, n = idx & 127;
        *(uint4*)&Bs[n*72 + kb*8] = *(const uint4*)(Bp + ((bK + kt*8 + kb)*npix + n0 + n)*8);
      }
    }
    __syncthreads();
    #pragma unroll
    for (int kk = 0; kk < 2; ++kk){
      s8v af[3]; s8v bfr[8];
      int ko = kk*32 + kg*8;
      #pragma unroll
      for (int mf = 0; mf < 3; ++mf) af[mf] = *(const s8v*)&As[(wm*48 + mf*16 + lr)*72 + ko];
      #pragma unroll
      for (int nf = 0; nf < 8; ++nf) bfr[nf] = *(const s8v*)&Bs[(nf*16 + lr)*72 + ko];
      #pragma unroll
      for (int mf = 0; mf < 3; ++mf)
        #pragma unroll
        for (int nf = 0; nf < 8; ++nf)
          acc[mf][nf] = mfma16(af[mf], bfr[nf], acc[mf][nf]);
    }
    __syncthreads();
  }
  int quad = lane >> 4;
  #pragma unroll
  for (int mf = 0; mf < 3; ++mf){
    int mb = m0 + wm*48 + mf*16 + quad*4;
    #pragma unroll
    for (int nf = 0; nf < 8; ++nf){
      int n = n0 + nf*16 + lr;
      if constexpr (PLANAR){
        float* o = (float*)outp;
        #pragma unroll
        for (int r2 = 0; r2 < 4; ++r2)
          o[((size_t)(b*outkb + mb + r2))*npix + n] = acc[mf][nf][r2];
      } else {
        bf16* o = (bf16*)outp;
        alignas(8) bf16 v4[4];
        #pragma unroll
        for (int r2 = 0; r2 < 4; ++r2) v4[r2] = __float2bfloat16(acc[mf][nf][r2]);
        *(uint2*)(o + ((size_t)(b*outkb + (mb >> 3))*npix + n)*8 + (mb & 7)) = *(const uint2*)v4;
      }
    }
  }
}

// ---------------- high branch: strip dw convs + 3x3 dw, fused ----------------
// xp packed [b][24][65536][8] -> hw3p packed [b][48][65536][8]
// kblk 0..23 = 3x3dw(dww branch), kblk 24..47 = 3x3dw(dwh branch)
__launch_bounds__(256, 4)
__global__ void k_high_dw(const bf16* __restrict__ xp,
    const float* __restrict__ wdww, const float* __restrict__ bdww,
    const float* __restrict__ wdwh, const float* __restrict__ bdwh,
    const float* __restrict__ w3, const float* __restrict__ b3,
    bf16* __restrict__ hw3p){
  __shared__ bf16 xs[28*29*8];      // [row][col pad29][8ch]
  __shared__ float dws[2*8*364];    // [branch][ch] planes; 18 rows x stride 20
  int t = blockIdx.x, cb = blockIdx.y, b = blockIdx.z, tid = threadIdx.x;
  int r0 = (t >> 4)*16, c0 = (t & 15)*16;

  // ---- stage x tile (28x28 halo) with padded row stride, uint4 per pixel ----
  const bf16* src = xp + ((size_t)(b*24 + cb))*NPIX*8;
  for (int i = tid; i < 784; i += 256){
    int r = i/28, c = i - r*28;
    int gr = r0 + r - 6, gc = c0 + c - 6;
    uint4 v = {0,0,0,0};
    if ((unsigned)gr < 256u && (unsigned)gc < 256u)
      v = *(const uint4*)(src + ((size_t)(gr*256 + gc))*8);
    *(uint4*)&xs[(r*29 + c)*8] = v;
  }
  __syncthreads();

  // ---- phase A: strip convs via register sliding window ----
  auto strip_task = [&](int task, bool isH){
    int ch = task & 7, idx = task >> 3;
    int cg = cb*8 + ch;
    const float* wsrc = isH ? (wdww + cg*11) : (wdwh + cg*11);
    float wv[11];
    #pragma unroll
    for (int j = 0; j < 11; ++j) wv[j] = wsrc[j];
    float bias = isH ? bdww[cg] : bdwh[cg];
    int base = isH ? ((idx + 5)*29)*8 + ch : (idx + 5)*8 + ch;
    int istr = isH ? 8 : 29*8;
    float vbuf[28];
    #pragma unroll
    for (int i = 0; i < 28; ++i)
      vbuf[i] = __bfloat162float(xs[base + i*istr]);
    int fixedv = (isH ? r0 : c0) + idx - 1;
    int varb   = (isH ? c0 : r0) - 1;
    bool fok = (unsigned)fixedv < 256u;
    float out[18];
    #pragma unroll
    for (int i = 0; i < 18; ++i){
      float s = bias;
      #pragma unroll
      for (int j = 0; j < 11; ++j) s += wv[j]*vbuf[i + j];
      bool ok = fok && ((unsigned)(varb + i) < 256u);
      out[i] = ok ? s : 0.f;
    }
    if (isH){
      float* ob = &dws[ch*364 + idx*20];
      #pragma unroll
      for (int q = 0; q < 4; ++q){
        f4 v; v[0] = out[q*4]; v[1] = out[q*4+1]; v[2] = out[q*4+2]; v[3] = out[q*4+3];
        *(f4*)(ob + q*4) = v;
      }
      f2 v2; v2[0] = out[16]; v2[1] = out[17];
      *(f2*)(ob + 16) = v2;
    } else {
      float* ob = &dws[(8 + ch)*364 + idx];
      #pragma unroll
      for (int i = 0; i < 18; ++i) ob[i*20] = out[i];
    }
  };
  {
    bool isH = tid < 144;
    int task = isH ? tid : tid - 144;   // H tasks 0..143, V tasks 0..111
    strip_task(task, isH);
    if (tid >= 224) strip_task(tid - 112, false);  // V tasks 112..143
  }
  __syncthreads();

  // ---- phase B: 3x3 combine, register sliding along the row ----
  {
    int branch = tid >> 7, rr = (tid >> 3) & 15, ch = tid & 7;
    int cg = cb*8 + ch;
    const float* wsrc = w3 + (branch*192 + cg)*9;
    float w[9];
    #pragma unroll
    for (int k = 0; k < 9; ++k) w[k] = wsrc[k];
    float bias = b3[branch*192 + cg];
    float acc[16];
    #pragma unroll
    for (int i = 0; i < 16; ++i) acc[i] = bias;
    const float* plane = &dws[(branch*8 + ch)*364];
    #pragma unroll
    for (int dr = 0; dr < 3; ++dr){
      const float* rp = plane + (rr + dr)*20;
      float rowv[18];
      #pragma unroll
      for (int q = 0; q < 4; ++q){
        f4 v = *(const f4*)(rp + q*4);
        rowv[q*4] = v[0]; rowv[q*4+1] = v[1]; rowv[q*4+2] = v[2]; rowv[q*4+3] = v[3];
      }
      {
        f2 v2 = *(const f2*)(rp + 16);
        rowv[16] = v2[0]; rowv[17] = v2[1];
      }
      #pragma unroll
      for (int dc = 0; dc < 3; ++dc){
        float wv = w[dr*3 + dc];
        #pragma unroll
        for (int i = 0; i < 16; ++i) acc[i] += wv * rowv[i + dc];
      }
    }
    bf16* o = hw3p + (((size_t)(b*48 + branch*24 + cb))*NPIX + (size_t)(r0 + rr)*256 + c0)*8 + ch;
    #pragma unroll
    for (int i = 0; i < 16; ++i) o[i*8] = __float2bfloat16(acc[i]);
  }
}

// ---------------- qkv depthwise 3x3 (+ v max/avg reduction for cb>=48) ----------------
__global__ void k_qkv_dw(const bf16* __restrict__ qkv0p, const float* __restrict__ wdw,
                         float* __restrict__ qkvd, float* __restrict__ vmax, float* __restrict__ vavg){
  __shared__ bf16 xs[34*34*8];
  __shared__ float red[256*8];
  int cb = blockIdx.x, b = blockIdx.y, tid = threadIdx.x;
  for (int i = tid; i < 1156; i += 256){
    int r = i/34, c = i - r*34;
    int gr = r - 1, gc = c - 1;
    uint4 v = {0,0,0,0};
    if ((unsigned)gr < 32u && (unsigned)gc < 32u)
      v = *(const uint4*)(qkv0p + (((size_t)(b*72 + cb))*NDOWN + gr*32 + gc)*8);
    *(uint4*)&xs[i*8] = v;
  }
  __syncthreads();
  float mxv[8], smv[8];
  #pragma unroll
  for (int ch = 0; ch < 8; ++ch){ mxv[ch] = -3.4e38f; smv[ch] = 0.f; }
  for (int j = 0; j < 4; ++j){
    int p = j*256 + tid;
    int r = p >> 5, c = p & 31;
    #pragma unroll
    for (int ch = 0; ch < 8; ++ch){
      float s = 0.f;
      #pragma unroll
      for (int dr = 0; dr < 3; ++dr)
        #pragma unroll
        for (int dc = 0; dc < 3; ++dc)
          s += wdw[(cb*8 + ch)*9 + dr*3 + dc] *
               __bfloat162float(xs[((r + dr)*34 + c + dc)*8 + ch]);
      qkvd[((size_t)(b*576 + cb*8 + ch))*NDOWN + p] = s;
      mxv[ch] = fmaxf(mxv[ch], s);
      smv[ch] += s;
    }
  }
  if (cb >= 48){
    #pragma unroll
    for (int ch = 0; ch < 8; ++ch) red[tid*8 + ch] = mxv[ch];
    __syncthreads();
    for (int st = 128; st > 0; st >>= 1){
      if (tid < st)
        #pragma unroll
        for (int ch = 0; ch < 8; ++ch)
          red[tid*8 + ch] = fmaxf(red[tid*8 + ch], red[(tid + st)*8 + ch]);
      __syncthreads();
    }
    if (tid < 8) vmax[b*192 + (cb - 48)*8 + tid] = red[tid];
    __syncthreads();
    #pragma unroll
    for (int ch = 0; ch < 8; ++ch) red[tid*8 + ch] = smv[ch];
    __syncthreads();
    for (int st = 128; st > 0; st >>= 1){
      if (tid < st)
        #pragma unroll
        for (int ch = 0; ch < 8; ++ch) red[tid*8 + ch] += red[(tid + st)*8 + ch];
      __syncthreads();
    }
    if (tid < 8) vavg[b*192 + (cb - 48)*8 + tid] = red[tid] * (1.0f/1024.0f);
  }
}

// ---------------- attention matrix: normalize q,k rows; softmax(temp * q_hat k_hat^T) ----------------
__global__ void k_attn(const float* __restrict__ qkvd, const float* __restrict__ temp,
                       float* __restrict__ attn){
  __shared__ float inv[48];
  __shared__ float sm[576];
  int bh = blockIdx.x;
  int b = bh >> 3, h = bh & 7;
  const float* qb = qkvd + ((size_t)(b*576 + h*24))*NDOWN;
  const float* kb = qkvd + ((size_t)(b*576 + 192 + h*24))*NDOWN;
  int tid = threadIdx.x, wave = tid >> 6, lane = tid & 63;
  for (int v = wave; v < 48; v += 4){
    const float* p = (v < 24) ? (qb + v*NDOWN) : (kb + (v - 24)*NDOWN);
    float s = 0.f;
    for (int i = lane; i < NDOWN; i += 64){ float xv = p[i]; s += xv*xv; }
    #pragma unroll
    for (int o = 32; o > 0; o >>= 1) s += __shfl_down(s, o);
    if (lane == 0) inv[v] = 1.0f / fmaxf(sqrtf(s), 1e-12f);
  }
  __syncthreads();
  float tp = temp[h];
  for (int pr = tid; pr < 576; pr += 256){
    int c = pr/24, d = pr - c*24;
    const float4* qp = (const float4*)(qb + c*NDOWN);
    const float4* kp = (const float4*)(kb + d*NDOWN);
    float s = 0.f;
    for (int i = 0; i < 256; ++i){
      float4 a = qp[i], e = kp[i];
      s += a.x*e.x + a.y*e.y + a.z*e.z + a.w*e.w;
    }
    sm[pr] = s * inv[c] * inv[24 + d] * tp;
  }
  __syncthreads();
  if (tid < 24){
    float mx = -3.4e38f;
    for (int d = 0; d < 24; ++d) mx = fmaxf(mx, sm[tid*24 + d]);
    float sum = 0.f;
    for (int d = 0; d < 24; ++d) sum += __expf(sm[tid*24 + d] - mx);
    float isum = 1.0f / sum;
    for (int d = 0; d < 24; ++d)
      attn[((size_t)bh)*576 + tid*24 + d] = __expf(sm[tid*24 + d] - mx) * isum;
  }
}

// ---------------- gate: W2 @ vmax + W3 @ vavg ----------------
__global__ void k_gate(const float* __restrict__ vmax, const float* __restrict__ vavg,
                       const float* __restrict__ w2, const float* __restrict__ w3,
                       float* __restrict__ gate){
  __shared__ float vm[192], va[192];
  int b = blockIdx.x, tid = threadIdx.x;
  if (tid < 192){ vm[tid] = vmax[b*192 + tid]; va[tid] = vavg[b*192 + tid]; }
  __syncthreads();
  if (tid < 192){
    float s = 0.f;
    const float* w2r = w2 + tid*192;
    const float* w3r = w3 + tid*192;
    for (int k = 0; k < 192; ++k) s += w2r[k]*vm[k] + w3r[k]*va[k];
    gate[b*192 + tid] = s;
  }
}

// ---------------- effective low-branch weights ----------------
// out_low = Wp_low @ (attn @ (gate .* x4))  ==  Weff_b @ x4 with
// Weff[b][o][d] = gate[b,d] * sum_cl Wp[o, 192+h*24+cl] * A[b,h,cl,dl],  h=d/24, dl=d%24.
// wfin[b] is the full per-batch [192][384] bf16 weight for the final GEMM:
// cols 0..191 = Wp high half (batch-independent), cols 192..383 = Weff.
// grid 32 = (b,h); 192 threads = o.
__global__ void k_weff(const float* __restrict__ attn, const float* __restrict__ gate,
                       const float* __restrict__ wp, bf16* __restrict__ wfin){
  __shared__ float A_s[576];
  int bh = blockIdx.x; int b = bh >> 3, h = bh & 7;
  int o = threadIdx.x;
  for (int i = o; i < 576; i += 192) A_s[i] = attn[(size_t)bh*576 + i];
  __syncthreads();
  const float* wrow = wp + (size_t)o*384;
  float wl[24];
  #pragma unroll
  for (int j = 0; j < 24; ++j) wl[j] = wrow[192 + h*24 + j];
  bf16* dst = wfin + ((size_t)b*192 + o)*384;
  #pragma unroll
  for (int j = 0; j < 24; ++j) dst[h*24 + j] = __float2bfloat16(wrow[h*24 + j]);
  #pragma unroll
  for (int dl = 0; dl < 24; ++dl){
    float s = 0.f;
    #pragma unroll
    for (int cl = 0; cl < 24; ++cl) s += wl[cl]*A_s[cl*24 + dl];
    dst[192 + h*24 + dl] = __float2bfloat16(s * gate[b*192 + h*24 + dl]);
  }
}

// ---------------- x4: depthwise 3x3 of conv4a output, packed->packed ----------------
// Replaces k_low's conv phase; attn-apply + gate folded into wfin (k_weff).
// Per-tap ds_read_b128 (conflict-free: dword starts (8r+4c)%32, 8 dwords/bank).
__global__ void k_x4(const bf16* __restrict__ x4ap, const float* __restrict__ w4b,
                     bf16* __restrict__ hlp){
  __shared__ bf16 xt[324*8];   // 18x18 halo, packed 8ch, stride 8 (16B aligned)
  __shared__ float wl4[72];
  int t = blockIdx.x, cb = blockIdx.y, b = blockIdx.z, tid = threadIdx.x;
  int r0 = (t >> 4)*16, c0 = (t & 15)*16;
  if (tid < 72) wl4[tid] = w4b[cb*72 + tid];
  for (int i = tid; i < 324; i += 256){
    int r = i/18, c = i - r*18;
    int gr = r0 + r - 1, gc = c0 + c - 1;
    uint4 v = {0,0,0,0};
    if ((unsigned)gr < 256u && (unsigned)gc < 256u)
      v = *(const uint4*)(x4ap + (((size_t)(b*24 + cb))*NPIX + gr*256 + gc)*8);
    *(uint4*)&xt[i*8] = v;
  }
  __syncthreads();
  {
    int r = tid >> 4, c = tid & 15;
    float acc[8] = {0,0,0,0,0,0,0,0};
    #pragma unroll
    for (int dr = 0; dr < 3; ++dr)
      #pragma unroll
      for (int dc = 0; dc < 3; ++dc){
        uint4 v = *(const uint4*)&xt[((r + dr)*18 + c + dc)*8];
        const bf16* c8 = (const bf16*)&v;
        int tap = dr*3 + dc;
        #pragma unroll
        for (int ch = 0; ch < 8; ++ch)
          acc[ch] += wl4[ch*9 + tap] * __bfloat162float(c8[ch]);
      }
    int n = (r0 + r)*256 + c0 + c;
    alignas(16) bf16 o8[8];
    #pragma unroll
    for (int ch = 0; ch < 8; ++ch) o8[ch] = __float2bfloat16(acc[ch]);
    *(uint4*)(hlp + (((size_t)(b*48 + 24 + cb))*NPIX + n)*8) = *(const uint4*)o8;
  }
}

extern "C" void kernel_launch(void* const* d_in, const int* in_sizes, int n_in,
                              void* d_out, int out_size, void* d_ws, size_t ws_size,
                              hipStream_t stream){
  const float* x        = (const float*)d_in[0];
  const float* w_dww    = (const float*)d_in[1];
  const float* b_dww    = (const float*)d_in[2];
  const float* w_dwh    = (const float*)d_in[3];
  const float* b_dwh    = (const float*)d_in[4];
  const float* w_dwhw   = (const float*)d_in[5];
  const float* b_dwhw   = (const float*)d_in[6];
  const float* w_conv1  = (const float*)d_in[7];
  const float* w_qkv    = (const float*)d_in[8];
  const float* w_qkvdw  = (const float*)d_in[9];
  const float* w_conv2  = (const float*)d_in[10];
  const float* w_conv3  = (const float*)d_in[11];
  const float* w_conv4a = (const float*)d_in[12];
  const float* w_conv4b = (const float*)d_in[13];
  const float* w_proj   = (const float*)d_in[14];
  const float* temp     = (const float*)d_in[15];

  char* ws = (char*)d_ws;
  size_t off = 0;
  auto take = [&](size_t bytes)->char*{
    char* r = ws + off;
    off = (off + bytes + 255) & ~(size_t)255;
    return r;
  };
  bf16*  xp    = (bf16*) take((size_t)4*192*65536*2);  // packed x
  bf16*  hw3p  = (bf16*) take((size_t)4*384*65536*2);  // packed high pre-conv1
  bf16*  hlp   = (bf16*) take((size_t)4*384*65536*2);  // packed [high|x4] proj input
  bf16*  x4ap  = (bf16*) take((size_t)4*192*65536*2);  // packed conv4a out
  bf16*  xdp   = (bf16*) take((size_t)4*192*1024*2);   // packed pooled x
  bf16*  qkv0p = (bf16*) take((size_t)4*576*1024*2);   // packed qkv 1x1 out
  float* qkvd  = (float*)take((size_t)4*576*1024*4);   // planar qkv post-dw
  float* attn  = (float*)take((size_t)4*8*576*4);
  float* vmax  = (float*)take((size_t)4*192*4);
  float* vavg  = (float*)take((size_t)4*192*4);
  float* gate  = (float*)take((size_t)4*192*4);
  bf16*  wbf   = (bf16*) take((size_t)294912*2);
  bf16*  wfin  = (bf16*) take((size_t)4*73728*2);      // per-batch final GEMM weights
  if (off > ws_size) return;  // workspace too small: fail loudly via absmax

  k_cast_w<<<1152, 256, 0, stream>>>(w_conv1, w_conv4a, w_proj, w_qkv, wbf);
  k_pack_x<<<dim3(64,24,4), 256, 0, stream>>>(x, xp);
  k_pool<<<dim3(32,24,4), 256, 0, stream>>>(xp, xdp);
  k_gemm<192,false><<<dim3(8,3,4), 256, 0, stream>>>(xdp, wbf + 184320, qkv0p, 1024, 72, 0);
  k_qkv_dw<<<dim3(72,4), 256, 0, stream>>>(qkv0p, w_qkvdw, qkvd, vmax, vavg);
  k_attn<<<32, 256, 0, stream>>>(qkvd, temp, attn);
  k_gate<<<4, 192, 0, stream>>>(vmax, vavg, w_conv2, w_conv3, gate);
  k_weff<<<32, 192, 0, stream>>>(attn, gate, w_proj, wfin);
  k_high_dw<<<dim3(256,24,4), 256, 0, stream>>>(xp, w_dww, b_dww, w_dwh, b_dwh, w_dwhw, b_dwhw, hw3p);
  k_gemm<384,false><<<dim3(512,1,4), 256, 0, stream>>>(hw3p, wbf, hlp, 65536, 48, 0);
  k_gemm<192,false><<<dim3(512,1,4), 256, 0, stream>>>(xp, wbf + 73728, x4ap, 65536, 24, 0);
  k_x4<<<dim3(256,24,4), 256, 0, stream>>>(x4ap, w_conv4b, hlp);
  k_gemm<384,true><<<dim3(512,1,4), 256, 0, stream>>>(hlp, wfin, d_out, 65536, 192, 73728);
}

// Round 7
// 906.479 us; speedup vs baseline: 1.3173x; 1.0050x over previous
//
#include <hip/hip_runtime.h>
#include <hip/hip_bf16.h>

typedef __hip_bfloat16 bf16;
typedef __attribute__((ext_vector_type(8))) short s8v;
typedef __attribute__((ext_vector_type(4))) float f4;
typedef __attribute__((ext_vector_type(2))) float f2;

#define DEVI __device__ __forceinline__

DEVI f4 mfma16(s8v a, s8v b, f4 c){
  return __builtin_amdgcn_mfma_f32_16x16x32_bf16(a, b, c, 0, 0, 0);
}

// packed fp32 fma: d = a*b + c per 32-bit half (v_pk_fma_f32, full-rate on CDNA)
DEVI f2 pkfma(f2 a, f2 b, f2 c){
  f2 d;
  asm("v_pk_fma_f32 %0, %1, %2, %3" : "=v"(d) : "v"(a), "v"(b), "v"(c));
  return d;
}

constexpr int NPIX = 65536;   // 256*256
constexpr int NDOWN = 1024;   // 32*32

// ---------------- cast weights to bf16 ----------------
// layout in wbf (elements): [0) w_conv1 73728 | [73728) w_conv4a 36864 |
//                           [110592) w_proj 73728 | [184320) w_qkv 110592
__global__ void k_cast_w(const float* __restrict__ w1, const float* __restrict__ w4a,
                         const float* __restrict__ wp, const float* __restrict__ wq,
                         bf16* __restrict__ out){
  int i = blockIdx.x*256 + threadIdx.x;
  if (i < 73728) out[i] = __float2bfloat16(w1[i]);
  else if (i < 110592) out[i] = __float2bfloat16(w4a[i - 73728]);
  else if (i < 184320) out[i] = __float2bfloat16(wp[i - 110592]);
  else if (i < 294912) out[i] = __float2bfloat16(wq[i - 184320]);
}

// ---------------- pack x: fp32 planar -> bf16 K-packed [b][24][65536][8] ----------------
__global__ void k_pack_x(const float* __restrict__ x, bf16* __restrict__ xp){
  __shared__ float t[8][1032];
  int b = blockIdx.z, cb = blockIdx.y, ns = blockIdx.x, tid = threadIdx.x;
  const float* src = x + ((size_t)(b*192 + cb*8))*NPIX + ns*1024;
  #pragma unroll
  for (int i = 0; i < 8; ++i){
    float4 v = *(const float4*)(src + (size_t)i*NPIX + tid*4);
    *(float4*)&t[i][tid*4] = v;
  }
  __syncthreads();
  bf16* dst = xp + (((size_t)(b*24 + cb))*NPIX + ns*1024)*8;
  #pragma unroll
  for (int j = 0; j < 4; ++j){
    int p = j*256 + tid;
    alignas(16) bf16 c8[8];
    #pragma unroll
    for (int i = 0; i < 8; ++i) c8[i] = __float2bfloat16(t[i][p]);
    *(uint4*)(dst + (size_t)p*8) = *(const uint4*)c8;
  }
}

// ---------------- avg-pool 8x8 -> packed bf16 [b][24][1024][8] ----------------
__global__ void k_pool(const bf16* __restrict__ xp, bf16* __restrict__ xdp){
  __shared__ float red[8][32][8];
  int b = blockIdx.z, cb = blockIdx.y, hd = blockIdx.x, tid = threadIdx.x;
  int r = tid >> 5, wd = tid & 31;
  const bf16* src = xp + (((size_t)(b*24 + cb))*NPIX + (hd*8 + r)*256 + wd*8)*8;
  float acc[8] = {0,0,0,0,0,0,0,0};
  #pragma unroll
  for (int ww = 0; ww < 8; ++ww){
    uint4 raw = *(const uint4*)(src + ww*8);
    const bf16* c8 = (const bf16*)&raw;
    #pragma unroll
    for (int i = 0; i < 8; ++i) acc[i] += __bfloat162float(c8[i]);
  }
  #pragma unroll
  for (int i = 0; i < 8; ++i) red[r][wd][i] = acc[i];
  __syncthreads();
  if (tid < 32){
    alignas(16) bf16 o8[8];
    #pragma unroll
    for (int i = 0; i < 8; ++i){
      float s = 0.f;
      #pragma unroll
      for (int rr = 0; rr < 8; ++rr) s += red[rr][tid][i];
      o8[i] = __float2bfloat16(s * (1.0f/64.0f));
    }
    *(uint4*)(xdp + (((size_t)(b*24 + cb))*NDOWN + hd*32 + tid)*8) = *(const uint4*)o8;
  }
}

// ---------------- MFMA GEMM: out[b][m][n] = sum_k W[m][k] * Bp[b][k][n] ----------------
// Bp is K-packed bf16 [b][K/8][npix][8]. Block tile 192(M) x 128(N): B is fetched
// from HBM exactly ONCE. 4 waves stacked along M (48 rows each), acc[3][8].
// PLANAR=false: packed bf16 out [b][outkb][npix][8]; PLANAR=true: planar fp32.
// wstride: per-batch W stride in elements (0 = shared weights).
template<int K, bool PLANAR>
__launch_bounds__(256, 2)
__global__ void k_gemm(const bf16* __restrict__ Bp, const bf16* __restrict__ W,
                       void* __restrict__ outp, int npix, int outkb, unsigned wstride){
  constexpr int KB8 = K/8;
  constexpr int NIT = K/64;
  __shared__ bf16 As[192*72];
  __shared__ bf16 Bs[128*72];
  int tid = threadIdx.x;
  int b = blockIdx.z;
  int m0 = blockIdx.y*192;
  int n0 = blockIdx.x*128;
  W += (size_t)b * wstride;
  int wave = tid >> 6, lane = tid & 63;
  int wm = wave;
  int lr = lane & 15, kg = lane >> 4;
  f4 acc[3][8] = {};
  const size_t bK = (size_t)b * KB8;
  for (int kt = 0; kt < NIT; ++kt){
    {
      int idx = tid;
      #pragma unroll
      for (int j = 0; j < 6; ++j, idx += 256){
        int m = idx >> 3, kc = idx & 7;
        *(uint4*)&As[m*72 + kc*8] = *(const uint4*)(W + (size_t)(m0 + m)*K + kt*64 + kc*8);
      }
      idx = tid;
      #pragma unroll
      for (int j = 0; j < 4; ++j, idx += 256){
        int kb = idx >> 7, n = idx & 127;
        *(uint4*)&Bs[n*72 + kb*8] = *(const uint4*)(Bp + ((bK + kt*8 + kb)*npix + n0 + n)*8);
      }
    }
    __syncthreads();
    #pragma unroll
    for (int kk = 0; kk < 2; ++kk){
      s8v af[3]; s8v bfr[8];
      int ko = kk*32 + kg*8;
      #pragma unroll
      for (int mf = 0; mf < 3; ++mf) af[mf] = *(const s8v*)&As[(wm*48 + mf*16 + lr)*72 + ko];
      #pragma unroll
      for (int nf = 0; nf < 8; ++nf) bfr[nf] = *(const s8v*)&Bs[(nf*16 + lr)*72 + ko];
      #pragma unroll
      for (int mf = 0; mf < 3; ++mf)
        #pragma unroll
        for (int nf = 0; nf < 8; ++nf)
          acc[mf][nf] = mfma16(af[mf], bfr[nf], acc[mf][nf]);
    }
    __syncthreads();
  }
  int quad = lane >> 4;
  #pragma unroll
  for (int mf = 0; mf < 3; ++mf){
    int mb = m0 + wm*48 + mf*16 + quad*4;
    #pragma unroll
    for (int nf = 0; nf < 8; ++nf){
      int n = n0 + nf*16 + lr;
      if constexpr (PLANAR){
        float* o = (float*)outp;
        #pragma unroll
        for (int r2 = 0; r2 < 4; ++r2)
          o[((size_t)(b*outkb + mb + r2))*npix + n] = acc[mf][nf][r2];
      } else {
        bf16* o = (bf16*)outp;
        alignas(8) bf16 v4[4];
        #pragma unroll
        for (int r2 = 0; r2 < 4; ++r2) v4[r2] = __float2bfloat16(acc[mf][nf][r2]);
        *(uint2*)(o + ((size_t)(b*outkb + (mb >> 3))*npix + n)*8 + (mb & 7)) = *(const uint2*)v4;
      }
    }
  }
}

// ---------------- high branch: strip dw convs + 3x3 dw, fused ----------------
// xp packed [b][24][65536][8] -> hw3p packed [b][48][65536][8]
// kblk 0..23 = 3x3dw(dww branch), kblk 24..47 = 3x3dw(dwh branch)
// v7: v_pk_fma_f32 inner loops (packed f32 = 2x rate; 157.3 TF peak requires it)
//     + phase-A balance: 32 extra V tasks run as 64 half-tasks on wave 3
//     (crit path 2.0 -> 1.5 tasks).
__launch_bounds__(256, 4)
__global__ void k_high_dw(const bf16* __restrict__ xp,
    const float* __restrict__ wdww, const float* __restrict__ bdww,
    const float* __restrict__ wdwh, const float* __restrict__ bdwh,
    const float* __restrict__ w3, const float* __restrict__ b3,
    bf16* __restrict__ hw3p){
  __shared__ bf16 xs[28*29*8];      // [row][col pad29][8ch]
  __shared__ float dws[2*8*364];    // [branch][ch] planes; 18 rows x stride 20
  int t = blockIdx.x, cb = blockIdx.y, b = blockIdx.z, tid = threadIdx.x;
  int r0 = (t >> 4)*16, c0 = (t & 15)*16;

  // ---- stage x tile (28x28 halo) with padded row stride, uint4 per pixel ----
  const bf16* src = xp + ((size_t)(b*24 + cb))*NPIX*8;
  for (int i = tid; i < 784; i += 256){
    int r = i/28, c = i - r*28;
    int gr = r0 + r - 6, gc = c0 + c - 6;
    uint4 v = {0,0,0,0};
    if ((unsigned)gr < 256u && (unsigned)gc < 256u)
      v = *(const uint4*)(src + ((size_t)(gr*256 + gc))*8);
    *(uint4*)&xs[(r*29 + c)*8] = v;
  }
  __syncthreads();

  // ---- phase A: strip convs, packed-pair sliding window ----
  // Outputs as 9 f2 pairs: even taps hit aligned pairs vb[], odd taps the
  // shifted pairs sb[]. 99 pk_fma vs 198 scalar fma.
  auto strip_full = [&](int task, bool isH){
    int ch = task & 7, idx = task >> 3;
    int cg = cb*8 + ch;
    const float* wsrc = isH ? (wdww + cg*11) : (wdwh + cg*11);
    float wv[11];
    #pragma unroll
    for (int j = 0; j < 11; ++j) wv[j] = wsrc[j];
    float bias = isH ? bdww[cg] : bdwh[cg];
    int base = isH ? ((idx + 5)*29)*8 + ch : (idx + 5)*8 + ch;
    int istr = isH ? 8 : 29*8;
    f2 vb[14];
    #pragma unroll
    for (int k = 0; k < 14; ++k){
      vb[k][0] = __bfloat162float(xs[base + (2*k)*istr]);
      vb[k][1] = __bfloat162float(xs[base + (2*k+1)*istr]);
    }
    f2 sb[13];
    #pragma unroll
    for (int k = 0; k < 13; ++k){ sb[k][0] = vb[k][1]; sb[k][1] = vb[k+1][0]; }
    f2 P[9];
    #pragma unroll
    for (int p = 0; p < 9; ++p){ P[p][0] = bias; P[p][1] = bias; }
    #pragma unroll
    for (int m = 0; m < 6; ++m){
      f2 wp; wp[0] = wv[2*m]; wp[1] = wv[2*m];
      #pragma unroll
      for (int p = 0; p < 9; ++p) P[p] = pkfma(vb[p + m], wp, P[p]);
    }
    #pragma unroll
    for (int m = 0; m < 5; ++m){
      f2 wp; wp[0] = wv[2*m+1]; wp[1] = wv[2*m+1];
      #pragma unroll
      for (int p = 0; p < 9; ++p) P[p] = pkfma(sb[p + m], wp, P[p]);
    }
    int fixedv = (isH ? r0 : c0) + idx - 1;
    int varb   = (isH ? c0 : r0) - 1;
    bool fok = (unsigned)fixedv < 256u;
    if (isH){
      float* ob = &dws[ch*364 + idx*20];
      #pragma unroll
      for (int p = 0; p < 9; ++p){
        f2 v = P[p];
        if (!(fok && (unsigned)(varb + 2*p)     < 256u)) v[0] = 0.f;
        if (!(fok && (unsigned)(varb + 2*p + 1) < 256u)) v[1] = 0.f;
        *(f2*)(ob + 2*p) = v;
      }
    } else {
      float* ob = &dws[(8 + ch)*364 + idx];
      #pragma unroll
      for (int p = 0; p < 9; ++p){
        ob[(2*p)*20]     = (fok && (unsigned)(varb + 2*p)     < 256u) ? P[p][0] : 0.f;
        ob[(2*p + 1)*20] = (fok && (unsigned)(varb + 2*p + 1) < 256u) ? P[p][1] : 0.f;
      }
    }
  };
  {
    bool isH = tid < 144;
    int task = isH ? tid : tid - 144;   // H tasks 0..143, V tasks 0..111
    strip_full(task, isH);
  }
  // extras: V tasks 112..143 split into 64 half-tasks (9 outputs) on wave 3
  if (tid >= 192){
    int e = tid - 192;            // 0..63
    int task = 112 + (e >> 1);    // V tasks 112..143
    int hh = e & 1;               // output rows [9*hh, 9*hh+9)
    int ch = task & 7, idx = task >> 3;
    int cg = cb*8 + ch;
    float wvv[11];
    #pragma unroll
    for (int j = 0; j < 11; ++j) wvv[j] = wdwh[cg*11 + j];
    float bias = bdwh[cg];
    int base = (idx + 5)*8 + ch + (hh*9)*232;   // istr = 29*8
    float vbuf[19];
    #pragma unroll
    for (int i = 0; i < 19; ++i) vbuf[i] = __bfloat162float(xs[base + i*232]);
    int fixedv = c0 + idx - 1;
    int varb = r0 - 1 + hh*9;
    bool fok = (unsigned)fixedv < 256u;
    float* ob = &dws[(8 + ch)*364 + idx + (hh*9)*20];
    #pragma unroll
    for (int i = 0; i < 9; ++i){
      float s = bias;
      #pragma unroll
      for (int j = 0; j < 11; ++j) s += wvv[j]*vbuf[i + j];
      bool ok = fok && ((unsigned)(varb + i) < 256u);
      ob[i*20] = ok ? s : 0.f;
    }
  }
  __syncthreads();

  // ---- phase B: 3x3 combine, packed pairs along the row ----
  // dc=0/2 hit aligned pairs ra[p]/ra[p+1] (pk_fma); dc=1 scalar on halves.
  {
    int branch = tid >> 7, rr = (tid >> 3) & 15, ch = tid & 7;
    int cg = cb*8 + ch;
    const float* wsrc = w3 + (branch*192 + cg)*9;
    float w[9];
    #pragma unroll
    for (int k = 0; k < 9; ++k) w[k] = wsrc[k];
    float bias = b3[branch*192 + cg];
    f2 P[8];
    #pragma unroll
    for (int p = 0; p < 8; ++p){ P[p][0] = bias; P[p][1] = bias; }
    const float* plane = &dws[(branch*8 + ch)*364];
    #pragma unroll
    for (int dr = 0; dr < 3; ++dr){
      const float* rp = plane + (rr + dr)*20;
      f2 ra[9];
      #pragma unroll
      for (int p = 0; p < 9; ++p) ra[p] = *(const f2*)(rp + 2*p);
      f2 w0p; w0p[0] = w[dr*3];     w0p[1] = w[dr*3];
      f2 w2p; w2p[0] = w[dr*3 + 2]; w2p[1] = w[dr*3 + 2];
      float w1 = w[dr*3 + 1];
      #pragma unroll
      for (int p = 0; p < 8; ++p){
        P[p] = pkfma(ra[p],     w0p, P[p]);
        P[p] = pkfma(ra[p + 1], w2p, P[p]);
        P[p][0] += w1 * ra[p][1];
        P[p][1] += w1 * ra[p + 1][0];
      }
    }
    bf16* o = hw3p + (((size_t)(b*48 + branch*24 + cb))*NPIX + (size_t)(r0 + rr)*256 + c0)*8 + ch;
    #pragma unroll
    for (int p = 0; p < 8; ++p){
      o[(2*p)*8]     = __float2bfloat16(P[p][0]);
      o[(2*p + 1)*8] = __float2bfloat16(P[p][1]);
    }
  }
}

// ---------------- qkv depthwise 3x3 (+ v max/avg reduction for cb>=48) ----------------
__global__ void k_qkv_dw(const bf16* __restrict__ qkv0p, const float* __restrict__ wdw,
                         float* __restrict__ qkvd, float* __restrict__ vmax, float* __restrict__ vavg){
  __shared__ bf16 xs[34*34*8];
  __shared__ float red[256*8];
  int cb = blockIdx.x, b = blockIdx.y, tid = threadIdx.x;
  for (int i = tid; i < 1156; i += 256){
    int r = i/34, c = i - r*34;
    int gr = r - 1, gc = c - 1;
    uint4 v = {0,0,0,0};
    if ((unsigned)gr < 32u && (unsigned)gc < 32u)
      v = *(const uint4*)(qkv0p + (((size_t)(b*72 + cb))*NDOWN + gr*32 + gc)*8);
    *(uint4*)&xs[i*8] = v;
  }
  __syncthreads();
  float mxv[8], smv[8];
  #pragma unroll
  for (int ch = 0; ch < 8; ++ch){ mxv[ch] = -3.4e38f; smv[ch] = 0.f; }
  for (int j = 0; j < 4; ++j){
    int p = j*256 + tid;
    int r = p >> 5, c = p & 31;
    #pragma unroll
    for (int ch = 0; ch < 8; ++ch){
      float s = 0.f;
      #pragma unroll
      for (int dr = 0; dr < 3; ++dr)
        #pragma unroll
        for (int dc = 0; dc < 3; ++dc)
          s += wdw[(cb*8 + ch)*9 + dr*3 + dc] *
               __bfloat162float(xs[((r + dr)*34 + c + dc)*8 + ch]);
      qkvd[((size_t)(b*576 + cb*8 + ch))*NDOWN + p] = s;
      mxv[ch] = fmaxf(mxv[ch], s);
      smv[ch] += s;
    }
  }
  if (cb >= 48){
    #pragma unroll
    for (int ch = 0; ch < 8; ++ch) red[tid*8 + ch] = mxv[ch];
    __syncthreads();
    for (int st = 128; st > 0; st >>= 1){
      if (tid < st)
        #pragma unroll
        for (int ch = 0; ch < 8; ++ch)
          red[tid*8 + ch] = fmaxf(red[tid*8 + ch], red[(tid + st)*8 + ch]);
      __syncthreads();
    }
    if (tid < 8) vmax[b*192 + (cb - 48)*8 + tid] = red[tid];
    __syncthreads();
    #pragma unroll
    for (int ch = 0; ch < 8; ++ch) red[tid*8 + ch] = smv[ch];
    __syncthreads();
    for (int st = 128; st > 0; st >>= 1){
      if (tid < st)
        #pragma unroll
        for (int ch = 0; ch < 8; ++ch) red[tid*8 + ch] += red[(tid + st)*8 + ch];
      __syncthreads();
    }
    if (tid < 8) vavg[b*192 + (cb - 48)*8 + tid] = red[tid] * (1.0f/1024.0f);
  }
}

// ---------------- attention matrix: normalize q,k rows; softmax(temp * q_hat k_hat^T) ----------------
__global__ void k_attn(const float* __restrict__ qkvd, const float* __restrict__ temp,
                       float* __restrict__ attn){
  __shared__ float inv[48];
  __shared__ float sm[576];
  int bh = blockIdx.x;
  int b = bh >> 3, h = bh & 7;
  const float* qb = qkvd + ((size_t)(b*576 + h*24))*NDOWN;
  const float* kb = qkvd + ((size_t)(b*576 + 192 + h*24))*NDOWN;
  int tid = threadIdx.x, wave = tid >> 6, lane = tid & 63;
  for (int v = wave; v < 48; v += 4){
    const float* p = (v < 24) ? (qb + v*NDOWN) : (kb + (v - 24)*NDOWN);
    float s = 0.f;
    for (int i = lane; i < NDOWN; i += 64){ float xv = p[i]; s += xv*xv; }
    #pragma unroll
    for (int o = 32; o > 0; o >>= 1) s += __shfl_down(s, o);
    if (lane == 0) inv[v] = 1.0f / fmaxf(sqrtf(s), 1e-12f);
  }
  __syncthreads();
  float tp = temp[h];
  for (int pr = tid; pr < 576; pr += 256){
    int c = pr/24, d = pr - c*24;
    const float4* qp = (const float4*)(qb + c*NDOWN);
    const float4* kp = (const float4*)(kb + d*NDOWN);
    float s = 0.f;
    for (int i = 0; i < 256; ++i){
      float4 a = qp[i], e = kp[i];
      s += a.x*e.x + a.y*e.y + a.z*e.z + a.w*e.w;
    }
    sm[pr] = s * inv[c] * inv[24 + d] * tp;
  }
  __syncthreads();
  if (tid < 24){
    float mx = -3.4e38f;
    for (int d = 0; d < 24; ++d) mx = fmaxf(mx, sm[tid*24 + d]);
    float sum = 0.f;
    for (int d = 0; d < 24; ++d) sum += __expf(sm[tid*24 + d] - mx);
    float isum = 1.0f / sum;
    for (int d = 0; d < 24; ++d)
      attn[((size_t)bh)*576 + tid*24 + d] = __expf(sm[tid*24 + d] - mx) * isum;
  }
}

// ---------------- gate: W2 @ vmax + W3 @ vavg ----------------
__global__ void k_gate(const float* __restrict__ vmax, const float* __restrict__ vavg,
                       const float* __restrict__ w2, const float* __restrict__ w3,
                       float* __restrict__ gate){
  __shared__ float vm[192], va[192];
  int b = blockIdx.x, tid = threadIdx.x;
  if (tid < 192){ vm[tid] = vmax[b*192 + tid]; va[tid] = vavg[b*192 + tid]; }
  __syncthreads();
  if (tid < 192){
    float s = 0.f;
    const float* w2r = w2 + tid*192;
    const float* w3r = w3 + tid*192;
    for (int k = 0; k < 192; ++k) s += w2r[k]*vm[k] + w3r[k]*va[k];
    gate[b*192 + tid] = s;
  }
}

// ---------------- effective low-branch weights ----------------
// out_low = Wp_low @ (attn @ (gate .* x4))  ==  Weff_b @ x4 with
// Weff[b][o][d] = gate[b,d] * sum_cl Wp[o, 192+h*24+cl] * A[b,h,cl,dl],  h=d/24, dl=d%24.
// wfin[b] is the full per-batch [192][384] bf16 weight for the final GEMM:
// cols 0..191 = Wp high half (batch-independent), cols 192..383 = Weff.
// grid 32 = (b,h); 192 threads = o.
__global__ void k_weff(const float* __restrict__ attn, const float* __restrict__ gate,
                       const float* __restrict__ wp, bf16* __restrict__ wfin){
  __shared__ float A_s[576];
  int bh = blockIdx.x; int b = bh >> 3, h = bh & 7;
  int o = threadIdx.x;
  for (int i = o; i < 576; i += 192) A_s[i] = attn[(size_t)bh*576 + i];
  __syncthreads();
  const float* wrow = wp + (size_t)o*384;
  float wl[24];
  #pragma unroll
  for (int j = 0; j < 24; ++j) wl[j] = wrow[192 + h*24 + j];
  bf16* dst = wfin + ((size_t)b*192 + o)*384;
  #pragma unroll
  for (int j = 0; j < 24; ++j) dst[h*24 + j] = __float2bfloat16(wrow[h*24 + j]);
  #pragma unroll
  for (int dl = 0; dl < 24; ++dl){
    float s = 0.f;
    #pragma unroll
    for (int cl = 0; cl < 24; ++cl) s += wl[cl]*A_s[cl*24 + dl];
    dst[192 + h*24 + dl] = __float2bfloat16(s * gate[b*192 + h*24 + dl]);
  }
}

// ---------------- x4: depthwise 3x3 of conv4a output, packed->packed ----------------
// Replaces k_low's conv phase; attn-apply + gate folded into wfin (k_weff).
// Per-tap ds_read_b128 (conflict-free: dword starts (8r+4c)%32, 8 dwords/bank).
__global__ void k_x4(const bf16* __restrict__ x4ap, const float* __restrict__ w4b,
                     bf16* __restrict__ hlp){
  __shared__ bf16 xt[324*8];   // 18x18 halo, packed 8ch, stride 8 (16B aligned)
  __shared__ float wl4[72];
  int t = blockIdx.x, cb = blockIdx.y, b = blockIdx.z, tid = threadIdx.x;
  int r0 = (t >> 4)*16, c0 = (t & 15)*16;
  if (tid < 72) wl4[tid] = w4b[cb*72 + tid];
  for (int i = tid; i < 324; i += 256){
    int r = i/18, c = i - r*18;
    int gr = r0 + r - 1, gc = c0 + c - 1;
    uint4 v = {0,0,0,0};
    if ((unsigned)gr < 256u && (unsigned)gc < 256u)
      v = *(const uint4*)(x4ap + (((size_t)(b*24 + cb))*NPIX + gr*256 + gc)*8);
    *(uint4*)&xt[i*8] = v;
  }
  __syncthreads();
  {
    int r = tid >> 4, c = tid & 15;
    float acc[8] = {0,0,0,0,0,0,0,0};
    #pragma unroll
    for (int dr = 0; dr < 3; ++dr)
      #pragma unroll
      for (int dc = 0; dc < 3; ++dc){
        uint4 v = *(const uint4*)&xt[((r + dr)*18 + c + dc)*8];
        const bf16* c8 = (const bf16*)&v;
        int tap = dr*3 + dc;
        #pragma unroll
        for (int ch = 0; ch < 8; ++ch)
          acc[ch] += wl4[ch*9 + tap] * __bfloat162float(c8[ch]);
      }
    int n = (r0 + r)*256 + c0 + c;
    alignas(16) bf16 o8[8];
    #pragma unroll
    for (int ch = 0; ch < 8; ++ch) o8[ch] = __float2bfloat16(acc[ch]);
    *(uint4*)(hlp + (((size_t)(b*48 + 24 + cb))*NPIX + n)*8) = *(const uint4*)o8;
  }
}

extern "C" void kernel_launch(void* const* d_in, const int* in_sizes, int n_in,
                              void* d_out, int out_size, void* d_ws, size_t ws_size,
                              hipStream_t stream){
  const float* x        = (const float*)d_in[0];
  const float* w_dww    = (const float*)d_in[1];
  const float* b_dww    = (const float*)d_in[2];
  const float* w_dwh    = (const float*)d_in[3];
  const float* b_dwh    = (const float*)d_in[4];
  const float* w_dwhw   = (const float*)d_in[5];
  const float* b_dwhw   = (const float*)d_in[6];
  const float* w_conv1  = (const float*)d_in[7];
  const float* w_qkv    = (const float*)d_in[8];
  const float* w_qkvdw  = (const float*)d_in[9];
  const float* w_conv2  = (const float*)d_in[10];
  const float* w_conv3  = (const float*)d_in[11];
  const float* w_conv4a = (const float*)d_in[12];
  const float* w_conv4b = (const float*)d_in[13];
  const float* w_proj   = (const float*)d_in[14];
  const float* temp     = (const float*)d_in[15];

  char* ws = (char*)d_ws;
  size_t off = 0;
  auto take = [&](size_t bytes)->char*{
    char* r = ws + off;
    off = (off + bytes + 255) & ~(size_t)255;
    return r;
  };
  bf16*  xp    = (bf16*) take((size_t)4*192*65536*2);  // packed x
  bf16*  hw3p  = (bf16*) take((size_t)4*384*65536*2);  // packed high pre-conv1
  bf16*  hlp   = (bf16*) take((size_t)4*384*65536*2);  // packed [high|x4] proj input
  bf16*  x4ap  = (bf16*) take((size_t)4*192*65536*2);  // packed conv4a out
  bf16*  xdp   = (bf16*) take((size_t)4*192*1024*2);   // packed pooled x
  bf16*  qkv0p = (bf16*) take((size_t)4*576*1024*2);   // packed qkv 1x1 out
  float* qkvd  = (float*)take((size_t)4*576*1024*4);   // planar qkv post-dw
  float* attn  = (float*)take((size_t)4*8*576*4);
  float* vmax  = (float*)take((size_t)4*192*4);
  float* vavg  = (float*)take((size_t)4*192*4);
  float* gate  = (float*)take((size_t)4*192*4);
  bf16*  wbf   = (bf16*) take((size_t)294912*2);
  bf16*  wfin  = (bf16*) take((size_t)4*73728*2);      // per-batch final GEMM weights
  if (off > ws_size) return;  // workspace too small: fail loudly via absmax

  k_cast_w<<<1152, 256, 0, stream>>>(w_conv1, w_conv4a, w_proj, w_qkv, wbf);
  k_pack_x<<<dim3(64,24,4), 256, 0, stream>>>(x, xp);
  k_pool<<<dim3(32,24,4), 256, 0, stream>>>(xp, xdp);
  k_gemm<192,false><<<dim3(8,3,4), 256, 0, stream>>>(xdp, wbf + 184320, qkv0p, 1024, 72, 0);
  k_qkv_dw<<<dim3(72,4), 256, 0, stream>>>(qkv0p, w_qkvdw, qkvd, vmax, vavg);
  k_attn<<<32, 256, 0, stream>>>(qkvd, temp, attn);
  k_gate<<<4, 192, 0, stream>>>(vmax, vavg, w_conv2, w_conv3, gate);
  k_weff<<<32, 192, 0, stream>>>(attn, gate, w_proj, wfin);
  k_high_dw<<<dim3(256,24,4), 256, 0, stream>>>(xp, w_dww, b_dww, w_dwh, b_dwh, w_dwhw, b_dwhw, hw3p);
  k_gemm<384,false><<<dim3(512,1,4), 256, 0, stream>>>(hw3p, wbf, hlp, 65536, 48, 0);
  k_gemm<192,false><<<dim3(512,1,4), 256, 0, stream>>>(xp, wbf + 73728, x4ap, 65536, 24, 0);
  k_x4<<<dim3(256,24,4), 256, 0, stream>>>(x4ap, w_conv4b, hlp);
  k_gemm<384,true><<<dim3(512,1,4), 256, 0, stream>>>(hlp, wfin, d_out, 65536, 192, 73728);
}